// Round 2
// baseline (1009.102 us; speedup 1.0000x reference)
//
#include <hip/hip_runtime.h>
#include <hip/hip_bf16.h>

typedef __hip_bfloat16 bf16;

__device__ __forceinline__ float sigf(float x){ return 1.f/(1.f+__expf(-x)); }

template<typename T> __device__ __forceinline__ float ldv(const T* p);
template<> __device__ __forceinline__ float ldv<float>(const float* p){ return *p; }
template<> __device__ __forceinline__ float ldv<bf16>(const bf16* p){ return __bfloat162float(*p); }
template<typename T> __device__ __forceinline__ T stv(float v);
template<> __device__ __forceinline__ float stv<float>(float v){ return v; }
template<> __device__ __forceinline__ bf16 stv<bf16>(float v){ return __float2bfloat16(v); }

#define ALPHA 0.2f
#define NEGV  -9e15f
#define GUARD if (flagp[0] != WANT) return;

// N=256 nodes, S=64 sensors, W=256 window, H=32 hidden.

// ---- K0: dtype detect. fp32 adj words are {0,0x3F800000}; bf16 packs pairs -> 0x3F803F80 occurs.
__global__ __launch_bounds__(256) void k0_detect(const unsigned* __restrict__ adjw,
                                                 int* __restrict__ flag){
  __shared__ int found;
  if (threadIdx.x == 0) found = 0;
  __syncthreads();
  int loc = 0;
  for (int i = threadIdx.x; i < 32768; i += 256)
    if (adjw[i] == 0x3F803F80u) loc = 1;
  if (loc) found = 1;
  __syncthreads();
  if (threadIdx.x == 0) flag[0] = found;   // 1 = bf16, 0 = fp32
}

// ---------------- K1: Wh_F[n] = x[n] (64x256) @ Fatt_W[n] (256x256) ----------------
template<int WANT, typename T>
__global__ __launch_bounds__(256) void k1_whf(const int* __restrict__ flagp,
                                              const T* __restrict__ x,
                                              const T* __restrict__ FW,
                                              float* __restrict__ WhF){
  GUARD;
  const int n = blockIdx.x, tid = threadIdx.x;
  __shared__ float xt[64*256];                 // xt[k*64+i] = x[n][i][k]  (64 KB)
  const T* xn = x + n*16384;
  for (int idx = tid; idx < 16384; idx += 256){
    int i = idx >> 8, k = idx & 255;
    xt[k*64 + i] = ldv(xn + idx);
  }
  __syncthreads();
  const int c = tid;                           // output column 0..255
  const T* Wn = FW + (size_t)n*65536;
  float acc[64];
#pragma unroll
  for (int i = 0; i < 64; ++i) acc[i] = 0.f;
#pragma unroll 2
  for (int k = 0; k < 256; ++k){
    float w = ldv(Wn + k*256 + c);             // coalesced
    const float* xc = &xt[k*64];               // broadcast
#pragma unroll
    for (int i = 0; i < 64; ++i) acc[i] = fmaf(xc[i], w, acc[i]);
  }
  float* o = WhF + n*16384;
#pragma unroll
  for (int i = 0; i < 64; ++i) o[i*256 + c] = acc[i];
}

// ---------------- K2: feature-GAT softmax + Fat = att @ Wh_F ----------------
template<int WANT, typename T>
__global__ __launch_bounds__(256) void k2_fat(const int* __restrict__ flagp,
                                              const float* __restrict__ WhF,
                                              const T* __restrict__ Fa,
                                              const T* __restrict__ Fadj,
                                              float* __restrict__ Fat){
  GUARD;
  const int n = blockIdx.x, tid = threadIdx.x;
  __shared__ float attT[64][68];               // attT[j][i] = att[i][j]
  __shared__ float f1s[64], f2s[64];
  const float* Wh = WhF + n*16384;
  { // f1/f2: thread (i=tid>>2, q=tid&3), shuffle-reduce over 4 lanes
    int i = tid >> 2, q = tid & 3;
    const T* an = Fa + n*512;
    float p1 = 0.f, p2 = 0.f;
    for (int cc = 0; cc < 64; ++cc){
      int c = (q<<6) + cc;
      float w = Wh[i*256 + c];
      p1 = fmaf(w, ldv(an + c), p1);
      p2 = fmaf(w, ldv(an + 256 + c), p2);
    }
    p1 += __shfl_xor(p1, 1); p1 += __shfl_xor(p1, 2);
    p2 += __shfl_xor(p2, 1); p2 += __shfl_xor(p2, 2);
    if (q == 0){ f1s[i] = p1; f2s[i] = p2; }
  }
  __syncthreads();
  if (tid < 64){                               // masked softmax, one row per thread
    const int r = tid;
    const float f1 = f1s[r];
    const T* adjr = Fadj + n*4096 + r*64;
    unsigned m0 = 0, m1 = 0;
#pragma unroll
    for (int j = 0; j < 32; ++j) if (ldv(adjr + j) > 0.f) m0 |= (1u << j);
#pragma unroll
    for (int j = 0; j < 32; ++j) if (ldv(adjr + 32 + j) > 0.f) m1 |= (1u << j);
    float m = -INFINITY;
#pragma unroll
    for (int j = 0; j < 64; ++j){
      float e = f1 + f2s[j]; e = (e > 0.f) ? e : ALPHA*e;
      unsigned bit = (j < 32) ? ((m0 >> j) & 1u) : ((m1 >> (j-32)) & 1u);
      e = bit ? e : NEGV;
      m = fmaxf(m, e);
    }
    float s = 0.f;
#pragma unroll
    for (int j = 0; j < 64; ++j){
      float e = f1 + f2s[j]; e = (e > 0.f) ? e : ALPHA*e;
      unsigned bit = (j < 32) ? ((m0 >> j) & 1u) : ((m1 >> (j-32)) & 1u);
      e = bit ? e : NEGV;
      s += __expf(e - m);
    }
    const float inv = 1.f / s;
#pragma unroll
    for (int j = 0; j < 64; ++j){
      float e = f1 + f2s[j]; e = (e > 0.f) ? e : ALPHA*e;
      unsigned bit = (j < 32) ? ((m0 >> j) & 1u) : ((m1 >> (j-32)) & 1u);
      e = bit ? e : NEGV;
      attT[j][r] = __expf(e - m) * inv;
    }
  }
  __syncthreads();
  const int c = tid;
  float acc[64];
#pragma unroll
  for (int i = 0; i < 64; ++i) acc[i] = 0.f;
#pragma unroll 2
  for (int k = 0; k < 64; ++k){
    float w = Wh[k*256 + c];                   // coalesced, L2-hot
    const float* ar = &attT[k][0];             // broadcast
#pragma unroll
    for (int i = 0; i < 64; ++i) acc[i] = fmaf(ar[i], w, acc[i]);
  }
  float* o = Fat + n*16384;
#pragma unroll
  for (int i = 0; i < 64; ++i) o[i*256 + c] = acc[i];
}

// ---------------- K3: Wh_T (transposed store) + Tf1/Tf2 ----------------
template<int WANT, typename T>
__global__ __launch_bounds__(256) void k3_wht(const int* __restrict__ flagp,
                                              const T* __restrict__ x,
                                              const T* __restrict__ TW,
                                              const T* __restrict__ Ta,
                                              float* __restrict__ WhTt,
                                              float* __restrict__ Tf1,
                                              float* __restrict__ Tf2){
  GUARD;
  const int n = blockIdx.x, tid = threadIdx.x;
  __shared__ float Wm[64][68];
  __shared__ float as[128];
  for (int idx = tid; idx < 4096; idx += 256) Wm[idx>>6][idx&63] = ldv(TW + n*4096 + idx);
  if (tid < 128) as[tid] = ldv(Ta + n*128 + tid);
  __syncthreads();
  const int i = tid;                           // row of h = x^T : 0..255
  const T* xn = x + n*16384;
  float acc[64];
#pragma unroll
  for (int c = 0; c < 64; ++c) acc[c] = 0.f;
#pragma unroll 2
  for (int k = 0; k < 64; ++k){
    float xv = ldv(xn + k*256 + i);            // h[i][k] = x[n][k][i], coalesced
    const float* wr = &Wm[k][0];               // broadcast
#pragma unroll
    for (int c = 0; c < 64; ++c) acc[c] = fmaf(xv, wr[c], acc[c]);
  }
  float f1 = 0.f, f2 = 0.f;
#pragma unroll
  for (int c = 0; c < 64; ++c){ f1 = fmaf(acc[c], as[c], f1); f2 = fmaf(acc[c], as[64+c], f2); }
  Tf1[n*256 + i] = f1; Tf2[n*256 + i] = f2;
  float* o = WhTt + n*16384;                   // [c][i], coalesced writes
#pragma unroll
  for (int c = 0; c < 64; ++c) o[c*256 + i] = acc[c];
}

// ------- generic GAT attention: rows=256, j=256, dout=64; Wh given transposed [64][256] -------
template<int WANT, typename T>
__global__ __launch_bounds__(256) void gat_att(const int* __restrict__ flagp,
                                               const float* __restrict__ WhtB, long long sW,
                                               const float* __restrict__ f1B,
                                               const float* __restrict__ f2B, long long sF,
                                               const T* __restrict__ adjB, long long sA,
                                               float* __restrict__ outTB, long long sO,
                                               T* __restrict__ dOut){
  GUARD;
  const int b = blockIdx.x, i = threadIdx.x;
  __shared__ float f2s[256];
  __shared__ unsigned maskS[256][9];           // per-thread adjacency bitmask
  __shared__ float wt[64][68];                 // Wh tile [j-tile][c]
  const float* Wht = WhtB + (size_t)b * sW;
  const float f1 = f1B[(size_t)b*sF + i];
  f2s[i] = f2B[(size_t)b*sF + i];
  const T* adjr = adjB + (size_t)b*sA + i*256;
  for (int w = 0; w < 8; ++w){
    unsigned mw = 0;
#pragma unroll
    for (int bb = 0; bb < 32; ++bb)
      if (ldv(adjr + (w<<5) + bb) > 0.f) mw |= (1u << bb);
    maskS[i][w] = mw;
  }
  __syncthreads();
  float m = -INFINITY;
  for (int w = 0; w < 8; ++w){
    const unsigned mw = maskS[i][w];
#pragma unroll
    for (int bb = 0; bb < 32; ++bb){
      float e = f1 + f2s[(w<<5)+bb]; e = (e > 0.f) ? e : ALPHA*e;
      e = ((mw >> bb) & 1u) ? e : NEGV;
      m = fmaxf(m, e);
    }
  }
  float s = 0.f;
  for (int w = 0; w < 8; ++w){
    const unsigned mw = maskS[i][w];
#pragma unroll
    for (int bb = 0; bb < 32; ++bb){
      float e = f1 + f2s[(w<<5)+bb]; e = (e > 0.f) ? e : ALPHA*e;
      e = ((mw >> bb) & 1u) ? e : NEGV;
      s += __expf(e - m);
    }
  }
  const float inv = 1.f / s;
  float acc[64];
#pragma unroll
  for (int c = 0; c < 64; ++c) acc[c] = 0.f;
  for (int jt = 0; jt < 4; ++jt){
    __syncthreads();
    for (int idx = i; idx < 4096; idx += 256){
      int c = idx >> 6, jj = idx & 63;
      wt[jj][c] = Wht[c*256 + (jt<<6) + jj];   // coalesced global read
    }
    __syncthreads();
    for (int jj = 0; jj < 64; ++jj){
      const int j = (jt<<6) + jj;
      float e = f1 + f2s[j]; e = (e > 0.f) ? e : ALPHA*e;
      e = ((maskS[i][j>>5] >> (j & 31)) & 1u) ? e : NEGV;
      const float p = __expf(e - m) * inv;
      const float* wr = &wt[jj][0];            // broadcast
#pragma unroll
      for (int c = 0; c < 64; ++c) acc[c] = fmaf(p, wr[c], acc[c]);
    }
  }
  if (dOut){
#pragma unroll
    for (int c = 0; c < 64; ++c) dOut[i*64 + c] = stv<T>(acc[c]);
  } else {
    float* o = outTB + (size_t)b * sO;         // transposed [c][i], coalesced
#pragma unroll
    for (int c = 0; c < 64; ++c) o[c*256 + i] = acc[c];
  }
}

// ---------------- K5: Gi0[n][t][g] = sum_k Wih0[n][g][k] * cat_at[n][t][k] ----------------
template<int WANT, typename T>
__global__ __launch_bounds__(256) void k5_gi0(const int* __restrict__ flagp,
                                              const float* __restrict__ Fat,
                                              const float* __restrict__ TatT,
                                              const T* __restrict__ x,
                                              const T* __restrict__ Wih0,
                                              float* __restrict__ Gi0){
  GUARD;
  const int n = blockIdx.x, tid = threadIdx.x;
  __shared__ float wl[96][68];                 // Wih0 k-tile
  __shared__ float cl[64][68];                 // cat_at k-tile
  const int b = tid >> 5, a = tid & 31;
  float acc[12][2];
#pragma unroll
  for (int gi = 0; gi < 12; ++gi){ acc[gi][0] = 0.f; acc[gi][1] = 0.f; }
  for (int kt = 0; kt < 12; ++kt){
    __syncthreads();
    const T* Wn = Wih0 + (size_t)n*73728 + (kt<<6);
    for (int idx = tid; idx < 6144; idx += 256){
      int g = idx >> 6, kk = idx & 63;
      wl[g][kk] = ldv(Wn + g*768 + kk);
    }
    const int seg = kt >> 2, ko = (kt & 3) << 6;  // 0:Fat 1:Tat^T 2:x
    const float* s32 = ((seg == 0) ? Fat : TatT) + n*16384 + ko;
    const T* sb = x + n*16384 + ko;
    for (int idx = tid; idx < 4096; idx += 256){
      int t = idx >> 6, kk = idx & 63;
      cl[t][kk] = (seg < 2) ? s32[t*256 + kk] : ldv(sb + t*256 + kk);
    }
    __syncthreads();
    for (int kk = 0; kk < 64; kk += 4){
      const float4 c0 = *(const float4*)&cl[a][kk];
      const float4 c1 = *(const float4*)&cl[a + 32][kk];
#pragma unroll
      for (int gi = 0; gi < 12; ++gi){
        const float4 wv = *(const float4*)&wl[b*12 + gi][kk];
        float a0 = acc[gi][0], a1v = acc[gi][1];
        a0  = fmaf(wv.x, c0.x, a0);  a0  = fmaf(wv.y, c0.y, a0);
        a0  = fmaf(wv.z, c0.z, a0);  a0  = fmaf(wv.w, c0.w, a0);
        a1v = fmaf(wv.x, c1.x, a1v); a1v = fmaf(wv.y, c1.y, a1v);
        a1v = fmaf(wv.z, c1.z, a1v); a1v = fmaf(wv.w, c1.w, a1v);
        acc[gi][0] = a0; acc[gi][1] = a1v;
      }
    }
  }
  float* o = Gi0 + n*6144;
#pragma unroll
  for (int gi = 0; gi < 12; ++gi){
    o[a*96 + b*12 + gi]        = acc[gi][0];
    o[(a + 32)*96 + b*12 + gi] = acc[gi][1];
  }
}

// ---------------- K6: sequential 2-layer GRU over 64 steps (per node) ----------------
template<int WANT, typename T>
__global__ __launch_bounds__(128) void k6_gru(const int* __restrict__ flagp,
                                              const float* __restrict__ Gi0,
                                              const T* __restrict__ Hpre,
                                              const T* __restrict__ Whh0,
                                              const T* __restrict__ bih0,
                                              const T* __restrict__ bhh0,
                                              const T* __restrict__ Wih1,
                                              const T* __restrict__ Whh1,
                                              const T* __restrict__ bih1,
                                              const T* __restrict__ bhh1,
                                              float* __restrict__ gru_out,
                                              T* __restrict__ dout){
  GUARD;
  const int n = blockIdx.x, tid = threadIdx.x;
  __shared__ float h0l[32], h1l[32], h0n[32], gis[96], ghs[96];
  float w0r[32], wi1r[32], wh1r[32];
  float bi0 = 0.f, bh0 = 0.f, bi1 = 0.f, bh1 = 0.f;
  const int g = tid;
  const bool act = (g < 96);
  if (act){
    const T* p0 = Whh0 + n*3072 + g*32;
    const T* p1 = Wih1 + n*3072 + g*32;
    const T* p2 = Whh1 + n*3072 + g*32;
#pragma unroll
    for (int h = 0; h < 32; ++h){ w0r[h] = ldv(p0 + h); wi1r[h] = ldv(p1 + h); wh1r[h] = ldv(p2 + h); }
    bi0 = ldv(bih0 + n*96 + g); bh0 = ldv(bhh0 + n*96 + g);
    bi1 = ldv(bih1 + n*96 + g); bh1 = ldv(bhh1 + n*96 + g);
  }
  if (tid < 32){ h0l[tid] = ldv(Hpre + n*32 + tid); h1l[tid] = ldv(Hpre + 8192 + n*32 + tid); }
  const float* gin = Gi0 + n*6144;
  float gi_cur = act ? gin[g] : 0.f;
  __syncthreads();
  for (int t = 0; t < 64; ++t){
    float gi_next = (act && t < 63) ? gin[(t+1)*96 + g] : 0.f;   // prefetch
    if (act){
      float gh = bh0;
#pragma unroll
      for (int h = 0; h < 32; ++h) gh = fmaf(w0r[h], h0l[h], gh);
      gis[g] = gi_cur + bi0;
      ghs[g] = gh;
    }
    __syncthreads();
    if (tid < 32){
      const int h = tid;
      float r = sigf(gis[h] + ghs[h]);
      float z = sigf(gis[32+h] + ghs[32+h]);
      float nn = tanhf(gis[64+h] + r*ghs[64+h]);
      h0n[h] = (1.f - z)*nn + z*h0l[h];
    }
    __syncthreads();
    if (act){
      float aa = bi1, bb = bh1;
#pragma unroll
      for (int h = 0; h < 32; ++h){ aa = fmaf(wi1r[h], h0n[h], aa); bb = fmaf(wh1r[h], h1l[h], bb); }
      gis[g] = aa; ghs[g] = bb;
    }
    __syncthreads();
    if (tid < 32){
      const int h = tid;
      float r = sigf(gis[h] + ghs[h]);
      float z = sigf(gis[32+h] + ghs[32+h]);
      float nn = tanhf(gis[64+h] + r*ghs[64+h]);
      float h1new = (1.f - z)*nn + z*h1l[h];
      h1l[h] = h1new; h0l[h] = h0n[h];
      gru_out[n*2048 + t*32 + h] = h1new;
    }
    __syncthreads();
    gi_cur = gi_next;
  }
  if (tid < 32){
    dout[16384 + n*32 + tid]        = stv<T>(h0l[tid]);   // cat_H[0]
    dout[16384 + 8192 + n*32 + tid] = stv<T>(h1l[tid]);   // cat_H[1]
  }
}

// ---------------- K7: fc1->relu->fc2->relu->fc3 => ct[n][s] ----------------
template<int WANT, typename T>
__global__ __launch_bounds__(256) void k7_fc(const int* __restrict__ flagp,
                                             const float* __restrict__ gru_out,
                                             const T* __restrict__ fc1w,
                                             const T* __restrict__ fc1b,
                                             const T* __restrict__ fc2w,
                                             const T* __restrict__ fc2b,
                                             const T* __restrict__ fc3w,
                                             const T* __restrict__ fc3b,
                                             float* __restrict__ ct){
  GUARD;
  const int n = blockIdx.x, tid = threadIdx.x;
  __shared__ float A[64][33];
  __shared__ float B[64][33];
  __shared__ float Wt[32][33];
  __shared__ float w3l[32];
  for (int idx = tid; idx < 2048; idx += 256) A[idx>>5][idx&31] = gru_out[n*2048 + idx];
  for (int idx = tid; idx < 1024; idx += 256) Wt[idx>>5][idx&31] = ldv(fc1w + n*1024 + idx);
  if (tid < 32) w3l[tid] = ldv(fc3w + n*32 + tid);
  __syncthreads();
  float r1[8];
#pragma unroll
  for (int ii = 0; ii < 8; ++ii){
    int o = tid + (ii<<8); int ss = o>>5, k = o&31;
    float v = ldv(fc1b + n*32 + k);
#pragma unroll
    for (int h = 0; h < 32; ++h) v = fmaf(A[ss][h], Wt[k][h], v);
    r1[ii] = (v > 0.f) ? v : 0.f;
  }
  __syncthreads();
#pragma unroll
  for (int ii = 0; ii < 8; ++ii){ int o = tid + (ii<<8); B[o>>5][o&31] = r1[ii]; }
  for (int idx = tid; idx < 1024; idx += 256) Wt[idx>>5][idx&31] = ldv(fc2w + n*1024 + idx);
  __syncthreads();
#pragma unroll
  for (int ii = 0; ii < 8; ++ii){
    int o = tid + (ii<<8); int ss = o>>5, k = o&31;
    float v = ldv(fc2b + n*32 + k);
#pragma unroll
    for (int h = 0; h < 32; ++h) v = fmaf(B[ss][h], Wt[k][h], v);
    A[ss][k] = (v > 0.f) ? v : 0.f;
  }
  __syncthreads();
  if (tid < 64){
    float v = ldv(fc3b + n);
#pragma unroll
    for (int h = 0; h < 32; ++h) v = fmaf(A[tid][h], w3l[h], v);
    ct[n*64 + tid] = v;
  }
}

// ---------------- K8a: Wh (transposed) + f1/f2 for out & out1 GATs ----------------
template<int WANT, typename T>
__global__ __launch_bounds__(256) void k8a(const int* __restrict__ flagp,
                                           const float* __restrict__ ct,
                                           const T* __restrict__ W0,
                                           const T* __restrict__ a0,
                                           const T* __restrict__ W1,
                                           const T* __restrict__ a1,
                                           float* __restrict__ WhAB,
                                           float* __restrict__ OF1,
                                           float* __restrict__ OF2){
  GUARD;
  const int gat = blockIdx.x, tid = threadIdx.x;
  __shared__ float ctt[16384];                 // ct transposed [k][i]  (64 KB)
  for (int idx = tid; idx < 16384; idx += 256){
    int i2 = idx >> 6, k = idx & 63;
    ctt[k*256 + i2] = ct[idx];
  }
  __syncthreads();
  const T* W = gat ? W1 : W0;
  const T* aa = gat ? a1 : a0;
  const int i = tid;
  float acc[64];
#pragma unroll
  for (int c = 0; c < 64; ++c) acc[c] = 0.f;
#pragma unroll 2
  for (int k = 0; k < 64; ++k){
    float v = ctt[k*256 + i];
    const T* wr = W + k*64;                    // block-uniform -> scalar loads
#pragma unroll
    for (int c = 0; c < 64; ++c) acc[c] = fmaf(v, ldv(wr + c), acc[c]);
  }
  float f1 = 0.f, f2 = 0.f;
#pragma unroll
  for (int c = 0; c < 64; ++c){ f1 = fmaf(acc[c], ldv(aa + c), f1); f2 = fmaf(acc[c], ldv(aa + 64 + c), f2); }
  OF1[gat*256 + i] = f1; OF2[gat*256 + i] = f2;
  float* o = WhAB + gat*16384;
#pragma unroll
  for (int c = 0; c < 64; ++c) o[c*256 + i] = acc[c];
}

// ---------------- K8c: Wh2 (transposed) + f1/f2 for final GAT ----------------
template<int WANT, typename T>
__global__ __launch_bounds__(256) void k8c(const int* __restrict__ flagp,
                                           const float* __restrict__ outT,
                                           const T* __restrict__ W2,
                                           const T* __restrict__ a2,
                                           float* __restrict__ Wh2,
                                           float* __restrict__ F1B,
                                           float* __restrict__ F2B){
  GUARD;
  const int blk = blockIdx.x, tid = threadIdx.x;
  __shared__ float red[64][9];
  const int il = tid & 63, cq = tid >> 6;
  const int i = blk*64 + il;
  float acc[16];
#pragma unroll
  for (int cc = 0; cc < 16; ++cc) acc[cc] = 0.f;
#pragma unroll 2
  for (int k = 0; k < 128; ++k){
    float v = outT[(k >> 6)*16384 + (k & 63)*256 + i];  // hcat[i][k], coalesced
    const T* wr = W2 + k*64 + cq*16;
#pragma unroll
    for (int cc = 0; cc < 16; ++cc) acc[cc] = fmaf(v, ldv(wr + cc), acc[cc]);
  }
#pragma unroll
  for (int cc = 0; cc < 16; ++cc) Wh2[(cq*16 + cc)*256 + i] = acc[cc];
  float p1 = 0.f, p2 = 0.f;
#pragma unroll
  for (int cc = 0; cc < 16; ++cc){
    p1 = fmaf(acc[cc], ldv(a2 + cq*16 + cc), p1);
    p2 = fmaf(acc[cc], ldv(a2 + 64 + cq*16 + cc), p2);
  }
  red[il][cq] = p1; red[il][4 + cq] = p2;
  __syncthreads();
  if (cq == 0){
    F1B[i] = red[il][0] + red[il][1] + red[il][2] + red[il][3];
    F2B[i] = red[il][4] + red[il][5] + red[il][6] + red[il][7];
  }
}

template<int WANT, typename T>
static void run_pipeline(void* const* d_in, void* d_out, float* ws, const int* flagp,
                         hipStream_t stream){
  const T* x     = (const T*)d_in[0];
  const T* Fadj  = (const T*)d_in[1];
  const T* Tadj  = (const T*)d_in[2];
  const T* adj   = (const T*)d_in[3];
  const T* Hpre  = (const T*)d_in[4];
  const T* FattW = (const T*)d_in[5];
  const T* Fatta = (const T*)d_in[6];
  const T* TattW = (const T*)d_in[7];
  const T* Tatta = (const T*)d_in[8];
  const T* Wih0  = (const T*)d_in[9];
  const T* Whh0  = (const T*)d_in[10];
  const T* bih0  = (const T*)d_in[11];
  const T* bhh0  = (const T*)d_in[12];
  const T* Wih1  = (const T*)d_in[13];
  const T* Whh1  = (const T*)d_in[14];
  const T* bih1  = (const T*)d_in[15];
  const T* bhh1  = (const T*)d_in[16];
  const T* fc1w  = (const T*)d_in[17];
  const T* fc1b  = (const T*)d_in[18];
  const T* fc2w  = (const T*)d_in[19];
  const T* fc2b  = (const T*)d_in[20];
  const T* fc3w  = (const T*)d_in[21];
  const T* fc3b  = (const T*)d_in[22];
  const T* oW    = (const T*)d_in[23];
  const T* oa    = (const T*)d_in[24];
  const T* o1W   = (const T*)d_in[25];
  const T* o1a   = (const T*)d_in[26];
  const T* o2W   = (const T*)d_in[27];
  const T* o2a   = (const T*)d_in[28];
  T* out = (T*)d_out;

  float* WhF  = ws;                          // 4194304 floats
  float* Fat  = ws + 4194304;                // 4194304
  float* WhT  = ws + 8388608;                // 4194304 (region C)
  float* TatT = WhF;                         // alias of region A
  float* Gi0  = WhT;                         // alias of region C (1572864)
  float* gruo = ws + 8388608 + 1572864;      // 524288
  float* Tf1  = ws + 12582912;               // 65536
  float* Tf2  = Tf1 + 65536;                 // 65536
  float* ctb  = Tf2 + 65536;                 // 16384
  float* WhAB = ctb + 16384;                 // 32768
  float* OF1  = WhAB + 32768;                // 512
  float* OF2  = OF1 + 512;                   // 512
  float* OUTT = OF2 + 512;                   // 32768
  float* WH2  = OUTT + 32768;                // 16384
  float* F1B  = WH2 + 16384;                 // 256
  float* F2B  = F1B + 256;                   // 256

  k1_whf<WANT,T><<<256, 256, 0, stream>>>(flagp, x, FattW, WhF);
  k2_fat<WANT,T><<<256, 256, 0, stream>>>(flagp, WhF, Fatta, Fadj, Fat);
  k3_wht<WANT,T><<<256, 256, 0, stream>>>(flagp, x, TattW, Tatta, WhT, Tf1, Tf2);
  gat_att<WANT,T><<<256, 256, 0, stream>>>(flagp, WhT, (long long)16384, Tf1, Tf2,
                                           (long long)256, Tadj, (long long)65536,
                                           TatT, (long long)16384, (T*)nullptr);
  k5_gi0<WANT,T><<<256, 256, 0, stream>>>(flagp, Fat, TatT, x, Wih0, Gi0);
  k6_gru<WANT,T><<<256, 128, 0, stream>>>(flagp, Gi0, Hpre, Whh0, bih0, bhh0,
                                          Wih1, Whh1, bih1, bhh1, gruo, out);
  k7_fc<WANT,T><<<256, 256, 0, stream>>>(flagp, gruo, fc1w, fc1b, fc2w, fc2b, fc3w, fc3b, ctb);
  k8a<WANT,T><<<2, 256, 0, stream>>>(flagp, ctb, oW, oa, o1W, o1a, WhAB, OF1, OF2);
  gat_att<WANT,T><<<2, 256, 0, stream>>>(flagp, WhAB, (long long)16384, OF1, OF2,
                                         (long long)256, adj, (long long)0,
                                         OUTT, (long long)16384, (T*)nullptr);
  k8c<WANT,T><<<4, 256, 0, stream>>>(flagp, OUTT, o2W, o2a, WH2, F1B, F2B);
  gat_att<WANT,T><<<1, 256, 0, stream>>>(flagp, WH2, (long long)0, F1B, F2B,
                                         (long long)0, adj, (long long)0,
                                         (float*)nullptr, (long long)0, out);
}

extern "C" void kernel_launch(void* const* d_in, const int* in_sizes, int n_in,
                              void* d_out, int out_size, void* d_ws, size_t ws_size,
                              hipStream_t stream){
  (void)in_sizes; (void)n_in; (void)out_size; (void)ws_size;
  float* ws = (float*)d_ws;
  int* flagp = (int*)(ws + 12813824);          // after all float regions (~51.3 MB total)
  k0_detect<<<1, 256, 0, stream>>>((const unsigned*)d_in[3], flagp);
  run_pipeline<0, float>(d_in, d_out, ws, flagp, stream);   // fp32 instantiation
  run_pipeline<1, bf16 >(d_in, d_out, ws, flagp, stream);   // bf16 instantiation
}

// Round 3
// 899.476 us; speedup vs baseline: 1.1219x; 1.1219x over previous
//
#include <hip/hip_runtime.h>
#include <hip/hip_bf16.h>

__device__ __forceinline__ float sigf(float x){ return 1.f/(1.f+__expf(-x)); }

#define ALPHA 0.2f
#define NEGV  -9e15f

// N=256 nodes, S=64 sensors, W=256 window, H=32 hidden. All fp32.
// Occupancy plan: every heavy kernel >= 8 waves/CU (block 512 @ grid 256, or
// block 256 @ grid 512). LDS <= 64 KB/block everywhere.

// ---- k_mask: pack adjacency fp32 (0/1) -> bitmask via wave ballot ----
__global__ __launch_bounds__(256) void k_mask(const float* __restrict__ src,
                                              unsigned* __restrict__ dst, int nelem){
  const int stride = gridDim.x * blockDim.x;
  const int lane = threadIdx.x & 63;
  for (int e = blockIdx.x*blockDim.x + threadIdx.x; e < nelem; e += stride){
    unsigned long long m = __ballot(src[e] > 0.f);
    if (lane == 0)       dst[e >> 5] = (unsigned)m;
    else if (lane == 32) dst[e >> 5] = (unsigned)(m >> 32);
  }
}

// ---- k3: Wh_T (transposed store) + Tf1/Tf2 partials. grid 512 = n*2 + c-half ----
__global__ __launch_bounds__(256) void k3_wht(const float* __restrict__ x,
                                              const float* __restrict__ TW,
                                              const float* __restrict__ Ta,
                                              float* __restrict__ WhTt,
                                              float* __restrict__ Tf1p,
                                              float* __restrict__ Tf2p){
  const int n = blockIdx.x >> 1, ch = blockIdx.x & 1, c0 = ch*32;
  const int tid = threadIdx.x;
  __shared__ float Wm[64][36];
  __shared__ float as1[32], as2[32];
  for (int idx = tid; idx < 2048; idx += 256){
    int k = idx >> 5, cc = idx & 31;
    Wm[k][cc] = TW[n*4096 + k*64 + c0 + cc];
  }
  if (tid < 32){ as1[tid] = Ta[n*128 + c0 + tid]; as2[tid] = Ta[n*128 + 64 + c0 + tid]; }
  __syncthreads();
  const int i = tid;
  const float* xn = x + n*16384;
  float acc[32];
#pragma unroll
  for (int c = 0; c < 32; ++c) acc[c] = 0.f;
#pragma unroll 2
  for (int k = 0; k < 64; ++k){
    float xv = xn[k*256 + i];                  // coalesced
    const float* wr = &Wm[k][0];               // broadcast b128
#pragma unroll
    for (int c = 0; c < 32; ++c) acc[c] = fmaf(xv, wr[c], acc[c]);
  }
  float f1 = 0.f, f2 = 0.f;
#pragma unroll
  for (int c = 0; c < 32; ++c){ f1 = fmaf(acc[c], as1[c], f1); f2 = fmaf(acc[c], as2[c], f2); }
  Tf1p[ch*65536 + n*256 + i] = f1;
  Tf2p[ch*65536 + n*256 + i] = f2;
  float* o = WhTt + n*16384;
#pragma unroll
  for (int c = 0; c < 32; ++c) o[(c0+c)*256 + i] = acc[c];
}

// ---- k4: time-GAT attention. grid 512 = n*2 + c-half, thread = window row i ----
__global__ __launch_bounds__(256) void k4_tat(const float* __restrict__ WhTt,
                                              const float* __restrict__ Tf1p,
                                              const float* __restrict__ Tf2p,
                                              const unsigned* __restrict__ maskT,
                                              float* __restrict__ TatT){
  const int n = blockIdx.x >> 1, ch = blockIdx.x & 1, c0 = ch*32;
  const int i = threadIdx.x;
  __shared__ float f2s[256];
  __shared__ float wt[64][36];
  const float f1 = Tf1p[n*256 + i] + Tf1p[65536 + n*256 + i];
  f2s[i] = Tf2p[n*256 + i] + Tf2p[65536 + n*256 + i];
  unsigned mw[8];
#pragma unroll
  for (int w = 0; w < 8; ++w) mw[w] = maskT[n*2048 + i*8 + w];
  __syncthreads();
  float m = -INFINITY;
  for (int w = 0; w < 8; ++w){
    const unsigned mk = mw[w];
#pragma unroll
    for (int bb = 0; bb < 32; ++bb){
      float e = f1 + f2s[(w<<5)+bb]; e = (e > 0.f) ? e : ALPHA*e;
      e = ((mk >> bb) & 1u) ? e : NEGV;
      m = fmaxf(m, e);
    }
  }
  float s = 0.f;
  for (int w = 0; w < 8; ++w){
    const unsigned mk = mw[w];
#pragma unroll
    for (int bb = 0; bb < 32; ++bb){
      float e = f1 + f2s[(w<<5)+bb]; e = (e > 0.f) ? e : ALPHA*e;
      e = ((mk >> bb) & 1u) ? e : NEGV;
      s += __expf(e - m);
    }
  }
  const float inv = 1.f / s;
  float acc[32];
#pragma unroll
  for (int c = 0; c < 32; ++c) acc[c] = 0.f;
  for (int jt = 0; jt < 4; ++jt){
    __syncthreads();
    for (int idx = i; idx < 2048; idx += 256){
      int cc = idx >> 6, jj = idx & 63;
      wt[jj][cc] = WhTt[n*16384 + (c0+cc)*256 + (jt<<6) + jj];   // coalesced
    }
    __syncthreads();
    for (int jj = 0; jj < 64; ++jj){
      const int j = (jt<<6) + jj;
      float e = f1 + f2s[j]; e = (e > 0.f) ? e : ALPHA*e;
      e = ((mw[j>>5] >> (j & 31)) & 1u) ? e : NEGV;
      const float p = __expf(e - m) * inv;
      const float* wr = &wt[jj][0];            // broadcast b128
#pragma unroll
      for (int c = 0; c < 32; ++c) acc[c] = fmaf(p, wr[c], acc[c]);
    }
  }
  float* o = TatT + n*16384;
#pragma unroll
  for (int c = 0; c < 32; ++c) o[(c0+c)*256 + i] = acc[c];
}

// ---- k1: Wh_F = x @ Fatt_W. grid 256, block 512 (two k-halves, LDS reduce) ----
__global__ __launch_bounds__(512) void k1_whf(const float* __restrict__ x,
                                              const float* __restrict__ FW,
                                              float* __restrict__ WhF){
  const int n = blockIdx.x, tid = threadIdx.x;
  __shared__ float xt[256][64];                // 64 KB; rotated layout (bank-friendly)
  const float* xn = x + n*16384;
  for (int idx = tid; idx < 16384; idx += 512){
    int i = idx >> 8, k = idx & 255;
    xt[k][(i + (k & 60)) & 63] = xn[idx];      // coalesced read; ~8-way store conflict (once)
  }
  __syncthreads();
  const int c = tid & 255, kg = tid >> 8;
  const float* Wn = FW + (size_t)n*65536;
  float acc[64];
#pragma unroll
  for (int i = 0; i < 64; ++i) acc[i] = 0.f;
  const int kbeg = kg*128, kend = kbeg + 128;
#pragma unroll 2
  for (int k = kbeg; k < kend; ++k){
    float w = Wn[k*256 + c];                   // coalesced
    const float4* xr = (const float4*)&xt[k][0];
    const int r4 = (k >> 2) & 15;
#pragma unroll
    for (int g = 0; g < 16; ++g){
      float4 v = xr[(g + r4) & 15];            // broadcast b128, uniform rotated index
      acc[4*g+0] = fmaf(v.x, w, acc[4*g+0]);
      acc[4*g+1] = fmaf(v.y, w, acc[4*g+1]);
      acc[4*g+2] = fmaf(v.z, w, acc[4*g+2]);
      acc[4*g+3] = fmaf(v.w, w, acc[4*g+3]);
    }
  }
  __syncthreads();
  float* buf = &xt[0][0];                      // reuse LDS as 64x256 reduce buffer
  if (kg == 1){
#pragma unroll
    for (int i = 0; i < 64; ++i) buf[i*256 + c] = acc[i];
  }
  __syncthreads();
  if (kg == 0){
    float* o = WhF + n*16384;
#pragma unroll
    for (int i = 0; i < 64; ++i) o[i*256 + c] = acc[i] + buf[i*256 + c];
  }
}

// ---- k2: feature-GAT softmax + Fat = att @ Wh. grid 256, block 512 (i-split) ----
__global__ __launch_bounds__(512) void k2_fat(const float* __restrict__ WhF,
                                              const float* __restrict__ Fa,
                                              const float* __restrict__ Fadj,
                                              float* __restrict__ Fat){
  const int n = blockIdx.x, tid = threadIdx.x;
  __shared__ float attT[64][68];               // attT[j][i]
  __shared__ float f1s[64], f2s[64];
  __shared__ float part[64][8][2];
  const float* Wh = WhF + n*16384;
  { // f1/f2: thread (i=tid>>3, q=tid&7) partial over 32 cols
    int i = tid >> 3, q = tid & 7;
    const float* an = Fa + n*512;
    float p1 = 0.f, p2 = 0.f;
    for (int cc = 0; cc < 32; ++cc){
      int c2 = q*32 + cc;
      float w = Wh[i*256 + c2];
      p1 = fmaf(w, an[c2], p1);
      p2 = fmaf(w, an[256 + c2], p2);
    }
    part[i][q][0] = p1; part[i][q][1] = p2;
  }
  __syncthreads();
  if (tid < 64){
    float s1 = 0.f, s2 = 0.f;
#pragma unroll
    for (int q = 0; q < 8; ++q){ s1 += part[tid][q][0]; s2 += part[tid][q][1]; }
    f1s[tid] = s1; f2s[tid] = s2;
  }
  __syncthreads();
  if (tid < 64){                               // masked softmax row -> attT column
    const int r = tid;
    const float f1 = f1s[r];
    const float* adjr = Fadj + n*4096 + r*64;
    unsigned m0 = 0, m1 = 0;
#pragma unroll
    for (int j = 0; j < 32; ++j) if (adjr[j] > 0.f) m0 |= (1u << j);
#pragma unroll
    for (int j = 0; j < 32; ++j) if (adjr[32+j] > 0.f) m1 |= (1u << j);
    float m = -INFINITY;
#pragma unroll
    for (int j = 0; j < 64; ++j){
      float e = f1 + f2s[j]; e = (e > 0.f) ? e : ALPHA*e;
      unsigned bit = (j < 32) ? ((m0 >> j) & 1u) : ((m1 >> (j-32)) & 1u);
      e = bit ? e : NEGV;
      m = fmaxf(m, e);
    }
    float s = 0.f;
#pragma unroll
    for (int j = 0; j < 64; ++j){
      float e = f1 + f2s[j]; e = (e > 0.f) ? e : ALPHA*e;
      unsigned bit = (j < 32) ? ((m0 >> j) & 1u) : ((m1 >> (j-32)) & 1u);
      e = bit ? e : NEGV;
      s += __expf(e - m);
    }
    const float inv = 1.f / s;
#pragma unroll
    for (int j = 0; j < 64; ++j){
      float e = f1 + f2s[j]; e = (e > 0.f) ? e : ALPHA*e;
      unsigned bit = (j < 32) ? ((m0 >> j) & 1u) : ((m1 >> (j-32)) & 1u);
      e = bit ? e : NEGV;
      attT[j][r] = __expf(e - m) * inv;
    }
  }
  __syncthreads();
  const int c = tid & 255, ih = tid >> 8;      // ih: 32-row half of output
  float acc[32];
#pragma unroll
  for (int i = 0; i < 32; ++i) acc[i] = 0.f;
#pragma unroll 2
  for (int j = 0; j < 64; ++j){
    float w = Wh[j*256 + c];                   // coalesced, L2-hot
    const float* ar = &attT[j][ih*32];         // broadcast b128 (16B-aligned)
#pragma unroll
    for (int i = 0; i < 32; ++i) acc[i] = fmaf(ar[i], w, acc[i]);
  }
  float* o = Fat + n*16384;
#pragma unroll
  for (int i = 0; i < 32; ++i) o[(ih*32 + i)*256 + c] = acc[i];
}

// ---- k5: Gi0 = cat_at @ Wih0^T. grid 256, block 512 (two k-halves, LDS reduce) ----
__global__ __launch_bounds__(512) void k5_gi0(const float* __restrict__ Fat,
                                              const float* __restrict__ TatT,
                                              const float* __restrict__ x,
                                              const float* __restrict__ Wih0,
                                              float* __restrict__ Gi0){
  const int n = blockIdx.x, tid = threadIdx.x;
  __shared__ float wl[2][96][36];              // 27648 B
  __shared__ float cl[2][64][36];              // 18432 B
  const int kg = tid >> 8, lt = tid & 255;
  const int b = lt >> 5, a = lt & 31;          // b: 12-gate group, a: t-lane
  float acc[12][2];
#pragma unroll
  for (int gi = 0; gi < 12; ++gi){ acc[gi][0] = 0.f; acc[gi][1] = 0.f; }
  for (int r = 0; r < 12; ++r){
    __syncthreads();
    const int kt = r*2 + kg;                   // 32-wide k tile, 0..23
    const int k0 = kt * 32;
    const float* Wn = Wih0 + (size_t)n*73728 + k0;
    for (int idx = lt; idx < 3072; idx += 256){
      int g = idx >> 5, kk = idx & 31;
      wl[kg][g][kk] = Wn[g*768 + kk];
    }
    const int seg = kt >> 3, ko = (kt & 7) * 32;   // 0:Fat 1:Tat^T 2:x
    const float* sp = (seg == 0) ? (Fat + n*16384 + ko)
                    : (seg == 1) ? (TatT + n*16384 + ko)
                                 : (x + n*16384 + ko);
    for (int idx = lt; idx < 2048; idx += 256){
      int t = idx >> 5, kk = idx & 31;
      cl[kg][t][kk] = sp[t*256 + kk];
    }
    __syncthreads();
    for (int kk = 0; kk < 32; kk += 4){
      const float4 c0v = *(const float4*)&cl[kg][a][kk];
      const float4 c1v = *(const float4*)&cl[kg][a + 32][kk];
#pragma unroll
      for (int gi = 0; gi < 12; ++gi){
        const float4 wv = *(const float4*)&wl[kg][b*12 + gi][kk];
        float a0 = acc[gi][0], a1v = acc[gi][1];
        a0  = fmaf(wv.x, c0v.x, a0);  a0  = fmaf(wv.y, c0v.y, a0);
        a0  = fmaf(wv.z, c0v.z, a0);  a0  = fmaf(wv.w, c0v.w, a0);
        a1v = fmaf(wv.x, c1v.x, a1v); a1v = fmaf(wv.y, c1v.y, a1v);
        a1v = fmaf(wv.z, c1v.z, a1v); a1v = fmaf(wv.w, c1v.w, a1v);
        acc[gi][0] = a0; acc[gi][1] = a1v;
      }
    }
  }
  __syncthreads();
  float* buf = &wl[0][0][0];                   // 6144 floats needed, fits in wl
  if (kg == 1){
#pragma unroll
    for (int gi = 0; gi < 12; ++gi){
      buf[lt*24 + gi*2]     = acc[gi][0];
      buf[lt*24 + gi*2 + 1] = acc[gi][1];
    }
  }
  __syncthreads();
  if (kg == 0){
    float* o = Gi0 + n*6144;
#pragma unroll
    for (int gi = 0; gi < 12; ++gi){
      o[a*96 + b*12 + gi]        = acc[gi][0] + buf[lt*24 + gi*2];
      o[(a + 32)*96 + b*12 + gi] = acc[gi][1] + buf[lt*24 + gi*2 + 1];
    }
  }
}

// ---- k6: 2-layer GRU (64 steps) + fused fc1/fc2/fc3. One wave per node ----
__global__ __launch_bounds__(64) void k6_gru(const float* __restrict__ Gi0,
                                             const float* __restrict__ Hpre,
                                             const float* __restrict__ Whh0,
                                             const float* __restrict__ bih0,
                                             const float* __restrict__ bhh0,
                                             const float* __restrict__ Wih1,
                                             const float* __restrict__ Whh1,
                                             const float* __restrict__ bih1,
                                             const float* __restrict__ bhh1,
                                             const float* __restrict__ fc1w,
                                             const float* __restrict__ fc1b,
                                             const float* __restrict__ fc2w,
                                             const float* __restrict__ fc2b,
                                             const float* __restrict__ fc3w,
                                             const float* __restrict__ fc3b,
                                             float* __restrict__ ct,
                                             float* __restrict__ dout){
  const int n = blockIdx.x, tid = threadIdx.x;
  __shared__ float h0l[32], h1l[32], h0n[32], gis[96], ghs[96];
  __shared__ float hist[64][33];
  __shared__ float Wst[32][33];
  __shared__ float b1s[32], b2s[32], w3s[32];
  const int gA = tid;                          // gate 0..63 (r:0-31, z:32-63)
  const bool hasB = (tid < 32);
  const int gB = 64 + tid;                     // n-gates for lanes 0..31
  float wA[32], wiA[32], whA[32], wB[32], wiB[32], whB[32];
#pragma unroll
  for (int h = 0; h < 32; ++h){
    wA[h]  = Whh0[n*3072 + gA*32 + h];
    wiA[h] = Wih1[n*3072 + gA*32 + h];
    whA[h] = Whh1[n*3072 + gA*32 + h];
  }
  if (hasB){
#pragma unroll
    for (int h = 0; h < 32; ++h){
      wB[h]  = Whh0[n*3072 + gB*32 + h];
      wiB[h] = Wih1[n*3072 + gB*32 + h];
      whB[h] = Whh1[n*3072 + gB*32 + h];
    }
  }
  const float biA = bih0[n*96 + gA], bhA = bhh0[n*96 + gA];
  const float bi1A = bih1[n*96 + gA], bh1A = bhh1[n*96 + gA];
  float biB = 0.f, bhB = 0.f, bi1B = 0.f, bh1B = 0.f;
  if (hasB){
    biB = bih0[n*96 + gB]; bhB = bhh0[n*96 + gB];
    bi1B = bih1[n*96 + gB]; bh1B = bhh1[n*96 + gB];
  }
  if (tid < 32){ h0l[tid] = Hpre[n*32 + tid]; h1l[tid] = Hpre[8192 + n*32 + tid]; }
  const float* gin = Gi0 + n*6144;
  float giA = gin[gA];
  float giB = hasB ? gin[gB] : 0.f;
  __syncthreads();
  for (int t = 0; t < 64; ++t){
    float giA_n = (t < 63) ? gin[(t+1)*96 + gA] : 0.f;
    float giB_n = (hasB && t < 63) ? gin[(t+1)*96 + gB] : 0.f;
    { // layer-0 hidden-dot, 4 independent chains
      float a0=0.f,a1=0.f,a2=0.f,a3=0.f;
#pragma unroll
      for (int h = 0; h < 32; h += 4){
        a0 = fmaf(wA[h],   h0l[h],   a0);
        a1 = fmaf(wA[h+1], h0l[h+1], a1);
        a2 = fmaf(wA[h+2], h0l[h+2], a2);
        a3 = fmaf(wA[h+3], h0l[h+3], a3);
      }
      gis[gA] = giA + biA;
      ghs[gA] = bhA + ((a0+a1)+(a2+a3));
      if (hasB){
        float c0=0.f,c1=0.f,c2=0.f,c3=0.f;
#pragma unroll
        for (int h = 0; h < 32; h += 4){
          c0 = fmaf(wB[h],   h0l[h],   c0);
          c1 = fmaf(wB[h+1], h0l[h+1], c1);
          c2 = fmaf(wB[h+2], h0l[h+2], c2);
          c3 = fmaf(wB[h+3], h0l[h+3], c3);
        }
        gis[gB] = giB + biB;
        ghs[gB] = bhB + ((c0+c1)+(c2+c3));
      }
    }
    __syncthreads();
    if (tid < 32){
      const int h = tid;
      float r = sigf(gis[h] + ghs[h]);
      float z = sigf(gis[32+h] + ghs[32+h]);
      float nn = tanhf(gis[64+h] + r*ghs[64+h]);
      h0n[h] = (1.f - z)*nn + z*h0l[h];
    }
    __syncthreads();
    { // layer-1 dots: gi1 from h0n, gh1 from h1l
      float a0=0.f,a1=0.f,a2=0.f,a3=0.f,b0=0.f,b1=0.f,b2=0.f,b3=0.f;
#pragma unroll
      for (int h = 0; h < 32; h += 4){
        a0 = fmaf(wiA[h],   h0n[h],   a0); b0 = fmaf(whA[h],   h1l[h],   b0);
        a1 = fmaf(wiA[h+1], h0n[h+1], a1); b1 = fmaf(whA[h+1], h1l[h+1], b1);
        a2 = fmaf(wiA[h+2], h0n[h+2], a2); b2 = fmaf(whA[h+2], h1l[h+2], b2);
        a3 = fmaf(wiA[h+3], h0n[h+3], a3); b3 = fmaf(whA[h+3], h1l[h+3], b3);
      }
      gis[gA] = bi1A + ((a0+a1)+(a2+a3));
      ghs[gA] = bh1A + ((b0+b1)+(b2+b3));
      if (hasB){
        float c0=0.f,c1=0.f,c2=0.f,c3=0.f,d0=0.f,d1=0.f,d2=0.f,d3=0.f;
#pragma unroll
        for (int h = 0; h < 32; h += 4){
          c0 = fmaf(wiB[h],   h0n[h],   c0); d0 = fmaf(whB[h],   h1l[h],   d0);
          c1 = fmaf(wiB[h+1], h0n[h+1], c1); d1 = fmaf(whB[h+1], h1l[h+1], d1);
          c2 = fmaf(wiB[h+2], h0n[h+2], c2); d2 = fmaf(whB[h+2], h1l[h+2], d2);
          c3 = fmaf(wiB[h+3], h0n[h+3], c3); d3 = fmaf(whB[h+3], h1l[h+3], d3);
        }
        gis[gB] = bi1B + ((c0+c1)+(c2+c3));
        ghs[gB] = bh1B + ((d0+d1)+(d2+d3));
      }
    }
    __syncthreads();
    if (tid < 32){
      const int h = tid;
      float r = sigf(gis[h] + ghs[h]);
      float z = sigf(gis[32+h] + ghs[32+h]);
      float nn = tanhf(gis[64+h] + r*ghs[64+h]);
      float h1new = (1.f - z)*nn + z*h1l[h];
      hist[t][h] = h1new;
      h1l[h] = h1new;
      h0l[h] = h0n[h];
    }
    __syncthreads();
    giA = giA_n; giB = giB_n;
  }
  if (tid < 32){
    dout[16384 + n*32 + tid]        = h0l[tid];   // cat_H[0]
    dout[16384 + 8192 + n*32 + tid] = h1l[tid];   // cat_H[1]
  }
  // ---- fused FC head: lane = sensor s (64) ----
  if (tid < 32){
    b1s[tid] = fc1b[n*32 + tid];
    b2s[tid] = fc2b[n*32 + tid];
    w3s[tid] = fc3w[n*32 + tid];
  }
  for (int idx = tid; idx < 1024; idx += 64) Wst[idx>>5][idx&31] = fc1w[n*1024 + idx];
  __syncthreads();
  float hr[32];
#pragma unroll
  for (int h = 0; h < 32; ++h) hr[h] = hist[tid][h];
  float r1[32];
#pragma unroll
  for (int k = 0; k < 32; ++k){
    float a0=0.f,a1=0.f,a2=0.f,a3=0.f;
#pragma unroll
    for (int h = 0; h < 32; h += 4){
      a0 = fmaf(hr[h],   Wst[k][h],   a0);
      a1 = fmaf(hr[h+1], Wst[k][h+1], a1);
      a2 = fmaf(hr[h+2], Wst[k][h+2], a2);
      a3 = fmaf(hr[h+3], Wst[k][h+3], a3);
    }
    float v = b1s[k] + ((a0+a1)+(a2+a3));
    r1[k] = v > 0.f ? v : 0.f;
  }
  __syncthreads();
  for (int idx = tid; idx < 1024; idx += 64) Wst[idx>>5][idx&31] = fc2w[n*1024 + idx];
  __syncthreads();
  float r2[32];
#pragma unroll
  for (int k = 0; k < 32; ++k){
    float a0=0.f,a1=0.f,a2=0.f,a3=0.f;
#pragma unroll
    for (int h = 0; h < 32; h += 4){
      a0 = fmaf(r1[h],   Wst[k][h],   a0);
      a1 = fmaf(r1[h+1], Wst[k][h+1], a1);
      a2 = fmaf(r1[h+2], Wst[k][h+2], a2);
      a3 = fmaf(r1[h+3], Wst[k][h+3], a3);
    }
    float v = b2s[k] + ((a0+a1)+(a2+a3));
    r2[k] = v > 0.f ? v : 0.f;
  }
  float v = fc3b[n];
#pragma unroll
  for (int h = 0; h < 32; ++h) v = fmaf(r2[h], w3s[h], v);
  ct[n*64 + tid] = v;
}

// ---- k8a: Wh (transposed) + f1/f2 for out & out1. grid 8 = gat*4 + row-quarter ----
__global__ __launch_bounds__(256) void k8a(const float* __restrict__ ct,
                                           const float* __restrict__ W0,
                                           const float* __restrict__ a0,
                                           const float* __restrict__ W1,
                                           const float* __restrict__ a1,
                                           float* __restrict__ WhABt,
                                           float* __restrict__ OF1,
                                           float* __restrict__ OF2){
  const int gat = blockIdx.x >> 2, rq = blockIdx.x & 3, r0 = rq*64;
  const int tid = threadIdx.x;
  const int ii = tid & 63, cq = tid >> 6;
  __shared__ float ctl[64][65];
  __shared__ float Wl[64][68];
  __shared__ float a1s[64], a2s[64];
  __shared__ float red[64][4][2];
  const float* W = gat ? W1 : W0;
  const float* aa = gat ? a1 : a0;
  for (int idx = tid; idx < 4096; idx += 256){
    int i2 = idx >> 6, k = idx & 63;
    ctl[i2][k] = ct[(r0 + i2)*64 + k];
  }
  for (int idx = tid; idx < 4096; idx += 256){
    int k = idx >> 6, c = idx & 63;
    Wl[k][c] = W[k*64 + c];
  }
  if (tid < 64){ a1s[tid] = aa[tid]; a2s[tid] = aa[64 + tid]; }
  __syncthreads();
  float acc[16];
#pragma unroll
  for (int c = 0; c < 16; ++c) acc[c] = 0.f;
#pragma unroll 2
  for (int k = 0; k < 64; ++k){
    float v = ctl[ii][k];
    const float* wr = &Wl[k][cq*16];
#pragma unroll
    for (int c = 0; c < 16; ++c) acc[c] = fmaf(v, wr[c], acc[c]);
  }
  float p1 = 0.f, p2 = 0.f;
#pragma unroll
  for (int c = 0; c < 16; ++c){
    p1 = fmaf(acc[c], a1s[cq*16 + c], p1);
    p2 = fmaf(acc[c], a2s[cq*16 + c], p2);
  }
  red[ii][cq][0] = p1; red[ii][cq][1] = p2;
  float* o = WhABt + gat*16384;
#pragma unroll
  for (int c = 0; c < 16; ++c) o[(cq*16 + c)*256 + r0 + ii] = acc[c];
  __syncthreads();
  if (cq == 0){
    OF1[gat*256 + r0 + ii] = red[ii][0][0] + red[ii][1][0] + red[ii][2][0] + red[ii][3][0];
    OF2[gat*256 + r0 + ii] = red[ii][0][1] + red[ii][1][1] + red[ii][2][1] + red[ii][3][1];
  }
}

// ---- k8b: out/out1 attention. grid 8 = gat*4 + c-tile(16) ----
__global__ __launch_bounds__(256) void k8b(const float* __restrict__ WhABt,
                                           const float* __restrict__ OF1,
                                           const float* __restrict__ OF2,
                                           const unsigned* __restrict__ maskA,
                                           float* __restrict__ OUTT){
  const int gat = blockIdx.x >> 2, c0 = (blockIdx.x & 3) * 16;
  const int i = threadIdx.x;
  __shared__ float f2s[256];
  __shared__ float wt[64][36];
  const float f1 = OF1[gat*256 + i];
  f2s[i] = OF2[gat*256 + i];
  unsigned mw[8];
#pragma unroll
  for (int w = 0; w < 8; ++w) mw[w] = maskA[i*8 + w];
  __syncthreads();
  float m = -INFINITY;
  for (int w = 0; w < 8; ++w){
    const unsigned mk = mw[w];
#pragma unroll
    for (int bb = 0; bb < 32; ++bb){
      float e = f1 + f2s[(w<<5)+bb]; e = (e > 0.f) ? e : ALPHA*e;
      e = ((mk >> bb) & 1u) ? e : NEGV;
      m = fmaxf(m, e);
    }
  }
  float s = 0.f;
  for (int w = 0; w < 8; ++w){
    const unsigned mk = mw[w];
#pragma unroll
    for (int bb = 0; bb < 32; ++bb){
      float e = f1 + f2s[(w<<5)+bb]; e = (e > 0.f) ? e : ALPHA*e;
      e = ((mk >> bb) & 1u) ? e : NEGV;
      s += __expf(e - m);
    }
  }
  const float inv = 1.f / s;
  float acc[16];
#pragma unroll
  for (int c = 0; c < 16; ++c) acc[c] = 0.f;
  for (int jt = 0; jt < 4; ++jt){
    __syncthreads();
    for (int idx = i; idx < 1024; idx += 256){
      int cc = idx >> 6, jj = idx & 63;
      wt[jj][cc] = WhABt[gat*16384 + (c0+cc)*256 + (jt<<6) + jj];
    }
    __syncthreads();
    for (int jj = 0; jj < 64; ++jj){
      const int j = (jt<<6) + jj;
      float e = f1 + f2s[j]; e = (e > 0.f) ? e : ALPHA*e;
      e = ((mw[j>>5] >> (j & 31)) & 1u) ? e : NEGV;
      const float p = __expf(e - m) * inv;
      const float* wr = &wt[jj][0];
#pragma unroll
      for (int c = 0; c < 16; ++c) acc[c] = fmaf(p, wr[c], acc[c]);
    }
  }
#pragma unroll
  for (int c = 0; c < 16; ++c) OUTT[gat*16384 + (c0+c)*256 + i] = acc[c];
}

// ---- k8c: Wh2 (transposed) + F1B/F2B. grid 8 = 32-row chunks ----
__global__ __launch_bounds__(256) void k8c(const float* __restrict__ OUTT,
                                           const float* __restrict__ W2,
                                           const float* __restrict__ a2,
                                           float* __restrict__ Wh2,
                                           float* __restrict__ F1B,
                                           float* __restrict__ F2B){
  const int r0 = blockIdx.x * 32;
  const int tid = threadIdx.x;
  const int ii = tid & 31, cq = tid >> 5;      // 8 groups x 8 cols
  __shared__ float W2l[128][68];
  __shared__ float a1s[64], a2s[64];
  __shared__ float red[32][8][2];
  for (int idx = tid; idx < 8192; idx += 256){
    int k = idx >> 6, c = idx & 63;
    W2l[k][c] = W2[k*64 + c];
  }
  if (tid < 64){ a1s[tid] = a2[tid]; a2s[tid] = a2[64 + tid]; }
  __syncthreads();
  float acc[8];
#pragma unroll
  for (int c = 0; c < 8; ++c) acc[c] = 0.f;
#pragma unroll 2
  for (int k = 0; k < 128; ++k){
    float v = OUTT[(k >> 6)*16384 + (k & 63)*256 + r0 + ii];
    const float* wr = &W2l[k][cq*8];
#pragma unroll
    for (int c = 0; c < 8; ++c) acc[c] = fmaf(v, wr[c], acc[c]);
  }
  float p1 = 0.f, p2 = 0.f;
#pragma unroll
  for (int c = 0; c < 8; ++c){
    p1 = fmaf(acc[c], a1s[cq*8 + c], p1);
    p2 = fmaf(acc[c], a2s[cq*8 + c], p2);
  }
  red[ii][cq][0] = p1; red[ii][cq][1] = p2;
#pragma unroll
  for (int c = 0; c < 8; ++c) Wh2[(cq*8 + c)*256 + r0 + ii] = acc[c];
  __syncthreads();
  if (cq == 0){
    float s1 = 0.f, s2 = 0.f;
#pragma unroll
    for (int q = 0; q < 8; ++q){ s1 += red[ii][q][0]; s2 += red[ii][q][1]; }
    F1B[r0 + ii] = s1; F2B[r0 + ii] = s2;
  }
}

// ---- k8d: final GAT -> d_out. grid 4 = c-tiles(16) ----
__global__ __launch_bounds__(256) void k8d(const float* __restrict__ Wh2,
                                           const float* __restrict__ F1B,
                                           const float* __restrict__ F2B,
                                           const unsigned* __restrict__ maskA,
                                           float* __restrict__ dOut){
  const int c0 = blockIdx.x * 16;
  const int i = threadIdx.x;
  __shared__ float f2s[256];
  __shared__ float wt[64][36];
  const float f1 = F1B[i];
  f2s[i] = F2B[i];
  unsigned mw[8];
#pragma unroll
  for (int w = 0; w < 8; ++w) mw[w] = maskA[i*8 + w];
  __syncthreads();
  float m = -INFINITY;
  for (int w = 0; w < 8; ++w){
    const unsigned mk = mw[w];
#pragma unroll
    for (int bb = 0; bb < 32; ++bb){
      float e = f1 + f2s[(w<<5)+bb]; e = (e > 0.f) ? e : ALPHA*e;
      e = ((mk >> bb) & 1u) ? e : NEGV;
      m = fmaxf(m, e);
    }
  }
  float s = 0.f;
  for (int w = 0; w < 8; ++w){
    const unsigned mk = mw[w];
#pragma unroll
    for (int bb = 0; bb < 32; ++bb){
      float e = f1 + f2s[(w<<5)+bb]; e = (e > 0.f) ? e : ALPHA*e;
      e = ((mk >> bb) & 1u) ? e : NEGV;
      s += __expf(e - m);
    }
  }
  const float inv = 1.f / s;
  float acc[16];
#pragma unroll
  for (int c = 0; c < 16; ++c) acc[c] = 0.f;
  for (int jt = 0; jt < 4; ++jt){
    __syncthreads();
    for (int idx = i; idx < 1024; idx += 256){
      int cc = idx >> 6, jj = idx & 63;
      wt[jj][cc] = Wh2[(c0+cc)*256 + (jt<<6) + jj];
    }
    __syncthreads();
    for (int jj = 0; jj < 64; ++jj){
      const int j = (jt<<6) + jj;
      float e = f1 + f2s[j]; e = (e > 0.f) ? e : ALPHA*e;
      e = ((mw[j>>5] >> (j & 31)) & 1u) ? e : NEGV;
      const float p = __expf(e - m) * inv;
      const float* wr = &wt[jj][0];
#pragma unroll
      for (int c = 0; c < 16; ++c) acc[c] = fmaf(p, wr[c], acc[c]);
    }
  }
#pragma unroll
  for (int c = 0; c < 16; ++c) dOut[i*64 + c0 + c] = acc[c];
}

extern "C" void kernel_launch(void* const* d_in, const int* in_sizes, int n_in,
                              void* d_out, int out_size, void* d_ws, size_t ws_size,
                              hipStream_t stream){
  (void)in_sizes; (void)n_in; (void)out_size; (void)ws_size;
  const float* x     = (const float*)d_in[0];
  const float* Fadj  = (const float*)d_in[1];
  const float* Tadj  = (const float*)d_in[2];
  const float* adj   = (const float*)d_in[3];
  const float* Hpre  = (const float*)d_in[4];
  const float* FattW = (const float*)d_in[5];
  const float* Fatta = (const float*)d_in[6];
  const float* TattW = (const float*)d_in[7];
  const float* Tatta = (const float*)d_in[8];
  const float* Wih0  = (const float*)d_in[9];
  const float* Whh0  = (const float*)d_in[10];
  const float* bih0  = (const float*)d_in[11];
  const float* bhh0  = (const float*)d_in[12];
  const float* Wih1  = (const float*)d_in[13];
  const float* Whh1  = (const float*)d_in[14];
  const float* bih1  = (const float*)d_in[15];
  const float* bhh1  = (const float*)d_in[16];
  const float* fc1w  = (const float*)d_in[17];
  const float* fc1b  = (const float*)d_in[18];
  const float* fc2w  = (const float*)d_in[19];
  const float* fc2b  = (const float*)d_in[20];
  const float* fc3w  = (const float*)d_in[21];
  const float* fc3b  = (const float*)d_in[22];
  const float* oW    = (const float*)d_in[23];
  const float* oa    = (const float*)d_in[24];
  const float* o1W   = (const float*)d_in[25];
  const float* o1a   = (const float*)d_in[26];
  const float* o2W   = (const float*)d_in[27];
  const float* o2a   = (const float*)d_in[28];
  float* out = (float*)d_out;

  float* ws = (float*)d_ws;
  // Regions (floats). Proven ws >= 12,813,825 floats (round-1 ran with that).
  // R0: WhTt -> WhF -> Gi0 ; R1: TatT -> tail ; R2: maskT+Tf partials -> Fat
  float* R0 = ws;
  float* R1 = ws + 4194304;
  float* R2 = ws + 8388608;
  unsigned* maskT = (unsigned*)R2;             // 524288 words
  float* Tf1p = R2 + 524288;                   // 2 x 65536
  float* Tf2p = R2 + 655360;                   // 2 x 65536
  unsigned* maskA = (unsigned*)(ws + 12582912);// 2048 words
  float* WhTt = R0;
  float* WhF  = R0;
  float* Gi0  = R0;
  float* TatT = R1;
  float* Fat  = R2;
  float* ctb   = R1;                           // tail (TatT dead after k5)
  float* WhABt = R1 + 16384;
  float* OF1   = R1 + 49152;
  float* OF2   = R1 + 49664;
  float* OUTT  = R1 + 50176;
  float* WH2   = R1 + 82944;
  float* F1B   = R1 + 99328;
  float* F2B   = R1 + 99584;

  k_mask<<<1024, 256, 0, stream>>>(Tadj, maskT, 16777216);
  k_mask<<<32, 256, 0, stream>>>(adj, maskA, 65536);
  k3_wht<<<512, 256, 0, stream>>>(x, TattW, Tatta, WhTt, Tf1p, Tf2p);
  k4_tat<<<512, 256, 0, stream>>>(WhTt, Tf1p, Tf2p, maskT, TatT);
  k1_whf<<<256, 512, 0, stream>>>(x, FattW, WhF);
  k2_fat<<<256, 512, 0, stream>>>(WhF, Fatta, Fadj, Fat);
  k5_gi0<<<256, 512, 0, stream>>>(Fat, TatT, x, Wih0, Gi0);
  k6_gru<<<256, 64, 0, stream>>>(Gi0, Hpre, Whh0, bih0, bhh0, Wih1, Whh1, bih1, bhh1,
                                 fc1w, fc1b, fc2w, fc2b, fc3w, fc3b, ctb, out);
  k8a<<<8, 256, 0, stream>>>(ctb, oW, oa, o1W, o1a, WhABt, OF1, OF2);
  k8b<<<8, 256, 0, stream>>>(WhABt, OF1, OF2, maskA, OUTT);
  k8c<<<8, 256, 0, stream>>>(OUTT, o2W, o2a, WH2, F1B, F2B);
  k8d<<<4, 256, 0, stream>>>(WH2, F1B, F2B, maskA, out);
}

// Round 4
// 883.011 us; speedup vs baseline: 1.1428x; 1.0186x over previous
//
#include <hip/hip_runtime.h>
#include <hip/hip_bf16.h>

__device__ __forceinline__ float sigf(float x){ return 1.f/(1.f+__expf(-x)); }
__device__ __forceinline__ float rdlane(float v, int j){
  return __int_as_float(__builtin_amdgcn_readlane(__float_as_int(v), j));
}

#define ALPHA 0.2f
#define NEGV  -9e15f

// N=256 nodes, S=64 sensors, W=256 window, H=32 hidden. All fp32.

// ---- k_mask: pack adjacency fp32 (0/1) -> bitmask via wave ballot ----
__global__ __launch_bounds__(256) void k_mask(const float* __restrict__ src,
                                              unsigned* __restrict__ dst, int nelem){
  const int stride = gridDim.x * blockDim.x;
  const int lane = threadIdx.x & 63;
  for (int e = blockIdx.x*blockDim.x + threadIdx.x; e < nelem; e += stride){
    unsigned long long m = __ballot(src[e] > 0.f);
    if (lane == 0)       dst[e >> 5] = (unsigned)m;
    else if (lane == 32) dst[e >> 5] = (unsigned)(m >> 32);
  }
}

// ---- k3: Wh_T (transposed store) + Tf1/Tf2 partials. grid 512 = n*2 + c-half ----
__global__ __launch_bounds__(256) void k3_wht(const float* __restrict__ x,
                                              const float* __restrict__ TW,
                                              const float* __restrict__ Ta,
                                              float* __restrict__ WhTt,
                                              float* __restrict__ Tf1p,
                                              float* __restrict__ Tf2p){
  const int n = blockIdx.x >> 1, ch = blockIdx.x & 1, c0 = ch*32;
  const int tid = threadIdx.x;
  __shared__ float Wm[64][36];
  __shared__ float as1[32], as2[32];
  for (int idx = tid; idx < 2048; idx += 256){
    int k = idx >> 5, cc = idx & 31;
    Wm[k][cc] = TW[n*4096 + k*64 + c0 + cc];
  }
  if (tid < 32){ as1[tid] = Ta[n*128 + c0 + tid]; as2[tid] = Ta[n*128 + 64 + c0 + tid]; }
  __syncthreads();
  const int i = tid;
  const float* xn = x + n*16384;
  float acc[32];
#pragma unroll
  for (int c = 0; c < 32; ++c) acc[c] = 0.f;
#pragma unroll 2
  for (int k = 0; k < 64; ++k){
    float xv = xn[k*256 + i];                  // coalesced
    const float* wr = &Wm[k][0];               // broadcast b128
#pragma unroll
    for (int c = 0; c < 32; ++c) acc[c] = fmaf(xv, wr[c], acc[c]);
  }
  float f1 = 0.f, f2 = 0.f;
#pragma unroll
  for (int c = 0; c < 32; ++c){ f1 = fmaf(acc[c], as1[c], f1); f2 = fmaf(acc[c], as2[c], f2); }
  Tf1p[ch*65536 + n*256 + i] = f1;
  Tf2p[ch*65536 + n*256 + i] = f2;
  float* o = WhTt + n*16384;
#pragma unroll
  for (int c = 0; c < 32; ++c) o[(c0+c)*256 + i] = acc[c];
}

// ---- k4: time-GAT attention. grid 512 = n*2 + c-half, thread = window row i ----
__global__ __launch_bounds__(256) void k4_tat(const float* __restrict__ WhTt,
                                              const float* __restrict__ Tf1p,
                                              const float* __restrict__ Tf2p,
                                              const unsigned* __restrict__ maskT,
                                              float* __restrict__ TatT){
  const int n = blockIdx.x >> 1, ch = blockIdx.x & 1, c0 = ch*32;
  const int i = threadIdx.x;
  __shared__ float f2s[256];
  __shared__ float wt[64][36];
  const float f1 = Tf1p[n*256 + i] + Tf1p[65536 + n*256 + i];
  f2s[i] = Tf2p[n*256 + i] + Tf2p[65536 + n*256 + i];
  unsigned mw[8];
#pragma unroll
  for (int w = 0; w < 8; ++w) mw[w] = maskT[n*2048 + i*8 + w];
  __syncthreads();
  float m = -INFINITY;
  for (int w = 0; w < 8; ++w){
    const unsigned mk = mw[w];
#pragma unroll
    for (int bb = 0; bb < 32; ++bb){
      float e = f1 + f2s[(w<<5)+bb]; e = (e > 0.f) ? e : ALPHA*e;
      e = ((mk >> bb) & 1u) ? e : NEGV;
      m = fmaxf(m, e);
    }
  }
  float s = 0.f;
  for (int w = 0; w < 8; ++w){
    const unsigned mk = mw[w];
#pragma unroll
    for (int bb = 0; bb < 32; ++bb){
      float e = f1 + f2s[(w<<5)+bb]; e = (e > 0.f) ? e : ALPHA*e;
      e = ((mk >> bb) & 1u) ? e : NEGV;
      s += __expf(e - m);
    }
  }
  const float inv = 1.f / s;
  float acc[32];
#pragma unroll
  for (int c = 0; c < 32; ++c) acc[c] = 0.f;
  for (int jt = 0; jt < 4; ++jt){
    __syncthreads();
    for (int idx = i; idx < 2048; idx += 256){
      int cc = idx >> 6, jj = idx & 63;
      wt[jj][cc] = WhTt[n*16384 + (c0+cc)*256 + (jt<<6) + jj];   // coalesced
    }
    __syncthreads();
    for (int jj = 0; jj < 64; ++jj){
      const int j = (jt<<6) + jj;
      float e = f1 + f2s[j]; e = (e > 0.f) ? e : ALPHA*e;
      e = ((mw[j>>5] >> (j & 31)) & 1u) ? e : NEGV;
      const float p = __expf(e - m) * inv;
      const float* wr = &wt[jj][0];            // broadcast b128
#pragma unroll
      for (int c = 0; c < 32; ++c) acc[c] = fmaf(p, wr[c], acc[c]);
    }
  }
  float* o = TatT + n*16384;
#pragma unroll
  for (int c = 0; c < 32; ++c) o[(c0+c)*256 + i] = acc[c];
}

// ---- k1: Wh_F = x @ Fatt_W. grid 256, block 512 (two k-halves, LDS reduce) ----
__global__ __launch_bounds__(512) void k1_whf(const float* __restrict__ x,
                                              const float* __restrict__ FW,
                                              float* __restrict__ WhF){
  const int n = blockIdx.x, tid = threadIdx.x;
  __shared__ float xt[256][64];                // 64 KB; rotated layout (bank-friendly)
  const float* xn = x + n*16384;
  for (int idx = tid; idx < 16384; idx += 512){
    int i = idx >> 8, k = idx & 255;
    xt[k][(i + (k & 60)) & 63] = xn[idx];      // coalesced read
  }
  __syncthreads();
  const int c = tid & 255, kg = tid >> 8;
  const float* Wn = FW + (size_t)n*65536;
  float acc[64];
#pragma unroll
  for (int i = 0; i < 64; ++i) acc[i] = 0.f;
  const int kbeg = kg*128, kend = kbeg + 128;
#pragma unroll 2
  for (int k = kbeg; k < kend; ++k){
    float w = Wn[k*256 + c];                   // coalesced
    const float4* xr = (const float4*)&xt[k][0];
    const int r4 = (k >> 2) & 15;
#pragma unroll
    for (int g = 0; g < 16; ++g){
      float4 v = xr[(g + r4) & 15];            // broadcast b128, uniform rotated index
      acc[4*g+0] = fmaf(v.x, w, acc[4*g+0]);
      acc[4*g+1] = fmaf(v.y, w, acc[4*g+1]);
      acc[4*g+2] = fmaf(v.z, w, acc[4*g+2]);
      acc[4*g+3] = fmaf(v.w, w, acc[4*g+3]);
    }
  }
  __syncthreads();
  float* buf = &xt[0][0];                      // reuse LDS as 64x256 reduce buffer
  if (kg == 1){
#pragma unroll
    for (int i = 0; i < 64; ++i) buf[i*256 + c] = acc[i];
  }
  __syncthreads();
  if (kg == 0){
    float* o = WhF + n*16384;
#pragma unroll
    for (int i = 0; i < 64; ++i) o[i*256 + c] = acc[i] + buf[i*256 + c];
  }
}

// ---- k2: feature-GAT softmax + Fat = att @ Wh. grid 256, block 512 (i-split) ----
__global__ __launch_bounds__(512) void k2_fat(const float* __restrict__ WhF,
                                              const float* __restrict__ Fa,
                                              const float* __restrict__ Fadj,
                                              float* __restrict__ Fat){
  const int n = blockIdx.x, tid = threadIdx.x;
  __shared__ float attT[64][68];               // attT[j][i]
  __shared__ float f1s[64], f2s[64];
  __shared__ float part[64][8][2];
  const float* Wh = WhF + n*16384;
  { // f1/f2: thread (i=tid>>3, q=tid&7) partial over 32 cols
    int i = tid >> 3, q = tid & 7;
    const float* an = Fa + n*512;
    float p1 = 0.f, p2 = 0.f;
    for (int cc = 0; cc < 32; ++cc){
      int c2 = q*32 + cc;
      float w = Wh[i*256 + c2];
      p1 = fmaf(w, an[c2], p1);
      p2 = fmaf(w, an[256 + c2], p2);
    }
    part[i][q][0] = p1; part[i][q][1] = p2;
  }
  __syncthreads();
  if (tid < 64){
    float s1 = 0.f, s2 = 0.f;
#pragma unroll
    for (int q = 0; q < 8; ++q){ s1 += part[tid][q][0]; s2 += part[tid][q][1]; }
    f1s[tid] = s1; f2s[tid] = s2;
  }
  __syncthreads();
  if (tid < 64){                               // masked softmax row -> attT column
    const int r = tid;
    const float f1 = f1s[r];
    const float* adjr = Fadj + n*4096 + r*64;
    unsigned m0 = 0, m1 = 0;
#pragma unroll
    for (int j = 0; j < 32; ++j) if (adjr[j] > 0.f) m0 |= (1u << j);
#pragma unroll
    for (int j = 0; j < 32; ++j) if (adjr[32+j] > 0.f) m1 |= (1u << j);
    float m = -INFINITY;
#pragma unroll
    for (int j = 0; j < 64; ++j){
      float e = f1 + f2s[j]; e = (e > 0.f) ? e : ALPHA*e;
      unsigned bit = (j < 32) ? ((m0 >> j) & 1u) : ((m1 >> (j-32)) & 1u);
      e = bit ? e : NEGV;
      m = fmaxf(m, e);
    }
    float s = 0.f;
#pragma unroll
    for (int j = 0; j < 64; ++j){
      float e = f1 + f2s[j]; e = (e > 0.f) ? e : ALPHA*e;
      unsigned bit = (j < 32) ? ((m0 >> j) & 1u) : ((m1 >> (j-32)) & 1u);
      e = bit ? e : NEGV;
      s += __expf(e - m);
    }
    const float inv = 1.f / s;
#pragma unroll
    for (int j = 0; j < 64; ++j){
      float e = f1 + f2s[j]; e = (e > 0.f) ? e : ALPHA*e;
      unsigned bit = (j < 32) ? ((m0 >> j) & 1u) : ((m1 >> (j-32)) & 1u);
      e = bit ? e : NEGV;
      attT[j][r] = __expf(e - m) * inv;
    }
  }
  __syncthreads();
  const int c = tid & 255, ih = tid >> 8;      // ih: 32-row half of output
  float acc[32];
#pragma unroll
  for (int i = 0; i < 32; ++i) acc[i] = 0.f;
#pragma unroll 2
  for (int j = 0; j < 64; ++j){
    float w = Wh[j*256 + c];                   // coalesced, L2-hot
    const float* ar = &attT[j][ih*32];         // broadcast b128 (16B-aligned)
#pragma unroll
    for (int i = 0; i < 32; ++i) acc[i] = fmaf(ar[i], w, acc[i]);
  }
  float* o = Fat + n*16384;
#pragma unroll
  for (int i = 0; i < 32; ++i) o[(ih*32 + i)*256 + c] = acc[i];
}

// ---- k5: Gi0 = cat_at @ Wih0^T. grid 256, block 512 (two k-halves, LDS reduce) ----
__global__ __launch_bounds__(512) void k5_gi0(const float* __restrict__ Fat,
                                              const float* __restrict__ TatT,
                                              const float* __restrict__ x,
                                              const float* __restrict__ Wih0,
                                              float* __restrict__ Gi0){
  const int n = blockIdx.x, tid = threadIdx.x;
  __shared__ float wl[2][96][36];              // 27648 B
  __shared__ float cl[2][64][36];              // 18432 B
  const int kg = tid >> 8, lt = tid & 255;
  const int b = lt >> 5, a = lt & 31;          // b: 12-gate group, a: t-lane
  float acc[12][2];
#pragma unroll
  for (int gi = 0; gi < 12; ++gi){ acc[gi][0] = 0.f; acc[gi][1] = 0.f; }
  for (int r = 0; r < 12; ++r){
    __syncthreads();
    const int kt = r*2 + kg;                   // 32-wide k tile, 0..23
    const int k0 = kt * 32;
    const float* Wn = Wih0 + (size_t)n*73728 + k0;
    for (int idx = lt; idx < 3072; idx += 256){
      int g = idx >> 5, kk = idx & 31;
      wl[kg][g][kk] = Wn[g*768 + kk];
    }
    const int seg = kt >> 3, ko = (kt & 7) * 32;   // 0:Fat 1:Tat^T 2:x
    const float* sp = (seg == 0) ? (Fat + n*16384 + ko)
                    : (seg == 1) ? (TatT + n*16384 + ko)
                                 : (x + n*16384 + ko);
    for (int idx = lt; idx < 2048; idx += 256){
      int t = idx >> 5, kk = idx & 31;
      cl[kg][t][kk] = sp[t*256 + kk];
    }
    __syncthreads();
    for (int kk = 0; kk < 32; kk += 4){
      const float4 c0v = *(const float4*)&cl[kg][a][kk];
      const float4 c1v = *(const float4*)&cl[kg][a + 32][kk];
#pragma unroll
      for (int gi = 0; gi < 12; ++gi){
        const float4 wv = *(const float4*)&wl[kg][b*12 + gi][kk];
        float a0 = acc[gi][0], a1v = acc[gi][1];
        a0  = fmaf(wv.x, c0v.x, a0);  a0  = fmaf(wv.y, c0v.y, a0);
        a0  = fmaf(wv.z, c0v.z, a0);  a0  = fmaf(wv.w, c0v.w, a0);
        a1v = fmaf(wv.x, c1v.x, a1v); a1v = fmaf(wv.y, c1v.y, a1v);
        a1v = fmaf(wv.z, c1v.z, a1v); a1v = fmaf(wv.w, c1v.w, a1v);
        acc[gi][0] = a0; acc[gi][1] = a1v;
      }
    }
  }
  __syncthreads();
  float* buf = &wl[0][0][0];                   // 6144 floats needed, fits in wl
  if (kg == 1){
#pragma unroll
    for (int gi = 0; gi < 12; ++gi){
      buf[lt*24 + gi*2]     = acc[gi][0];
      buf[lt*24 + gi*2 + 1] = acc[gi][1];
    }
  }
  __syncthreads();
  if (kg == 0){
    float* o = Gi0 + n*6144;
#pragma unroll
    for (int gi = 0; gi < 12; ++gi){
      o[a*96 + b*12 + gi]        = acc[gi][0] + buf[lt*24 + gi*2];
      o[(a + 32)*96 + b*12 + gi] = acc[gi][1] + buf[lt*24 + gi*2 + 1];
    }
  }
}

// ---- k6: 2-layer GRU (64 steps), register-resident, barrier-free recurrence ----
// One wave per node. Lane l owns gates {l, 64+(l&31)} (n-gate duplicated across
// half-waves). h0/h1 replicated per-lane as unrolled register arrays, refreshed
// by v_readlane broadcasts (no LDS, no __syncthreads in the loop). Fused FC head.
__global__ __launch_bounds__(64, 1) void k6_gru(const float* __restrict__ Gi0,
                                             const float* __restrict__ Hpre,
                                             const float* __restrict__ Whh0,
                                             const float* __restrict__ bih0,
                                             const float* __restrict__ bhh0,
                                             const float* __restrict__ Wih1,
                                             const float* __restrict__ Whh1,
                                             const float* __restrict__ bih1,
                                             const float* __restrict__ bhh1,
                                             const float* __restrict__ fc1w,
                                             const float* __restrict__ fc1b,
                                             const float* __restrict__ fc2w,
                                             const float* __restrict__ fc2b,
                                             const float* __restrict__ fc3w,
                                             const float* __restrict__ fc3b,
                                             float* __restrict__ ct,
                                             float* __restrict__ dout){
  const int n = blockIdx.x, l = threadIdx.x;
  const int h = l & 31;
  const bool lower = (l < 32);
  __shared__ float hist[64][33];
  __shared__ float Wst[32][33];
  __shared__ float b1s[32], b2s[32], w3s[32];
  // weight rows in registers: A = gate l (r/z), B = gate 64+h (n, duplicated)
  float wA[32], wB[32], wiA[32], wiB[32], whA[32], whB[32];
  {
    const float* W0  = Whh0 + n*3072;
    const float* Wi1 = Wih1 + n*3072;
    const float* Wh1 = Whh1 + n*3072;
#pragma unroll
    for (int k = 0; k < 32; ++k){
      wA[k]  = W0[l*32 + k];
      wB[k]  = W0[(64+h)*32 + k];
      wiA[k] = Wi1[l*32 + k];
      wiB[k] = Wi1[(64+h)*32 + k];
      whA[k] = Wh1[l*32 + k];
      whB[k] = Wh1[(64+h)*32 + k];
    }
  }
  const float biA  = bih0[n*96 + l],        bhA  = bhh0[n*96 + l];
  const float biB  = bih0[n*96 + 64 + h],   bhB  = bhh0[n*96 + 64 + h];
  const float bi1A = bih1[n*96 + l],        bh1A = bhh1[n*96 + l];
  const float bi1B = bih1[n*96 + 64 + h],   bh1B = bhh1[n*96 + 64 + h];
  // replicated hidden state (constant-index only!), own-value copies for updates
  float hr0[32], hr1[32];
  float h0own = Hpre[n*32 + h];
  float h1own = Hpre[8192 + n*32 + h];
#pragma unroll
  for (int j = 0; j < 32; ++j){ hr0[j] = rdlane(h0own, j); hr1[j] = rdlane(h1own, j); }
  const float* gin = Gi0 + n*6144;
  float giA = gin[l], giB = gin[64 + h];
  for (int t = 0; t < 64; ++t){
    float giA_n = 0.f, giB_n = 0.f;
    if (t < 63){ giA_n = gin[(t+1)*96 + l]; giB_n = gin[(t+1)*96 + 64 + h]; }
    // ---- layer 0: pure-register dots ----
    float a0=0.f,a1=0.f,a2=0.f,a3=0.f, b0=0.f,b1=0.f,b2=0.f,b3=0.f;
#pragma unroll
    for (int k = 0; k < 32; k += 4){
      a0 = fmaf(wA[k],   hr0[k],   a0); b0 = fmaf(wB[k],   hr0[k],   b0);
      a1 = fmaf(wA[k+1], hr0[k+1], a1); b1 = fmaf(wB[k+1], hr0[k+1], b1);
      a2 = fmaf(wA[k+2], hr0[k+2], a2); b2 = fmaf(wB[k+2], hr0[k+2], b2);
      a3 = fmaf(wA[k+3], hr0[k+3], a3); b3 = fmaf(wB[k+3], hr0[k+3], b3);
    }
    float vA = giA + biA + bhA + ((a0+a1)+(a2+a3));   // r-pre (lower) / z-pre (upper)
    float sA = sigf(vA);
    float ot = __shfl_xor(sA, 32);
    float r = lower ? sA : ot;
    float z = lower ? ot : sA;
    float ghB = bhB + ((b0+b1)+(b2+b3));
    float nn = tanhf(giB + biB + r*ghB);
    float h0new = (1.f - z)*nn + z*h0own;             // every lane: value for h=l&31
#pragma unroll
    for (int j = 0; j < 32; ++j) hr0[j] = rdlane(h0new, j);
    // ---- layer 1 ----
    float c0=0.f,c1=0.f,c2=0.f,c3=0.f, d0=0.f,d1=0.f,d2=0.f,d3=0.f;
    float e0=0.f,e1=0.f,e2=0.f,e3=0.f, f0=0.f,f1v=0.f,f2v=0.f,f3=0.f;
#pragma unroll
    for (int k = 0; k < 32; k += 4){
      c0 = fmaf(wiA[k],   hr0[k],   c0); d0 = fmaf(whA[k],   hr1[k],   d0);
      c1 = fmaf(wiA[k+1], hr0[k+1], c1); d1 = fmaf(whA[k+1], hr1[k+1], d1);
      c2 = fmaf(wiA[k+2], hr0[k+2], c2); d2 = fmaf(whA[k+2], hr1[k+2], d2);
      c3 = fmaf(wiA[k+3], hr0[k+3], c3); d3 = fmaf(whA[k+3], hr1[k+3], d3);
      e0 = fmaf(wiB[k],   hr0[k],   e0); f0  = fmaf(whB[k],   hr1[k],   f0);
      e1 = fmaf(wiB[k+1], hr0[k+1], e1); f1v = fmaf(whB[k+1], hr1[k+1], f1v);
      e2 = fmaf(wiB[k+2], hr0[k+2], e2); f2v = fmaf(whB[k+2], hr1[k+2], f2v);
      e3 = fmaf(wiB[k+3], hr0[k+3], e3); f3  = fmaf(whB[k+3], hr1[k+3], f3);
    }
    float vA1 = bi1A + ((c0+c1)+(c2+c3)) + bh1A + ((d0+d1)+(d2+d3));
    float sA1 = sigf(vA1);
    float ot1 = __shfl_xor(sA1, 32);
    float r1 = lower ? sA1 : ot1;
    float z1 = lower ? ot1 : sA1;
    float gi1B = bi1B + ((e0+e1)+(e2+e3));
    float gh1B = bh1B + ((f0+f1v)+(f2v+f3));
    float nn1 = tanhf(gi1B + r1*gh1B);
    float h1new = (1.f - z1)*nn1 + z1*h1own;
#pragma unroll
    for (int j = 0; j < 32; ++j) hr1[j] = rdlane(h1new, j);
    if (lower) hist[t][l] = h1new;                    // no read until after loop
    h0own = h0new; h1own = h1new;
    giA = giA_n; giB = giB_n;
  }
  if (lower){
    dout[16384 + n*32 + l]        = h0own;            // cat_H[0]
    dout[16384 + 8192 + n*32 + l] = h1own;            // cat_H[1]
  }
  // ---- fused FC head: lane = sensor s (64) ----
  if (lower){
    b1s[l] = fc1b[n*32 + l];
    b2s[l] = fc2b[n*32 + l];
    w3s[l] = fc3w[n*32 + l];
  }
  for (int idx = l; idx < 1024; idx += 64) Wst[idx>>5][idx&31] = fc1w[n*1024 + idx];
  __syncthreads();
  float hr[32];
#pragma unroll
  for (int k = 0; k < 32; ++k) hr[k] = hist[l][k];
  float r1a[32];
#pragma unroll
  for (int k = 0; k < 32; ++k){
    float a0=0.f,a1=0.f,a2=0.f,a3=0.f;
#pragma unroll
    for (int q = 0; q < 32; q += 4){
      a0 = fmaf(hr[q],   Wst[k][q],   a0);
      a1 = fmaf(hr[q+1], Wst[k][q+1], a1);
      a2 = fmaf(hr[q+2], Wst[k][q+2], a2);
      a3 = fmaf(hr[q+3], Wst[k][q+3], a3);
    }
    float v = b1s[k] + ((a0+a1)+(a2+a3));
    r1a[k] = v > 0.f ? v : 0.f;
  }
  __syncthreads();
  for (int idx = l; idx < 1024; idx += 64) Wst[idx>>5][idx&31] = fc2w[n*1024 + idx];
  __syncthreads();
  float r2a[32];
#pragma unroll
  for (int k = 0; k < 32; ++k){
    float a0=0.f,a1=0.f,a2=0.f,a3=0.f;
#pragma unroll
    for (int q = 0; q < 32; q += 4){
      a0 = fmaf(r1a[q],   Wst[k][q],   a0);
      a1 = fmaf(r1a[q+1], Wst[k][q+1], a1);
      a2 = fmaf(r1a[q+2], Wst[k][q+2], a2);
      a3 = fmaf(r1a[q+3], Wst[k][q+3], a3);
    }
    float v = b2s[k] + ((a0+a1)+(a2+a3));
    r2a[k] = v > 0.f ? v : 0.f;
  }
  float v = fc3b[n];
#pragma unroll
  for (int k = 0; k < 32; ++k) v = fmaf(r2a[k], w3s[k], v);
  ct[n*64 + l] = v;
}

// ---- k8a: Wh (transposed) + f1/f2 for out & out1. grid 8 = gat*4 + row-quarter ----
__global__ __launch_bounds__(256) void k8a(const float* __restrict__ ct,
                                           const float* __restrict__ W0,
                                           const float* __restrict__ a0,
                                           const float* __restrict__ W1,
                                           const float* __restrict__ a1,
                                           float* __restrict__ WhABt,
                                           float* __restrict__ OF1,
                                           float* __restrict__ OF2){
  const int gat = blockIdx.x >> 2, rq = blockIdx.x & 3, r0 = rq*64;
  const int tid = threadIdx.x;
  const int ii = tid & 63, cq = tid >> 6;
  __shared__ float ctl[64][65];
  __shared__ float Wl[64][68];
  __shared__ float a1s[64], a2s[64];
  __shared__ float red[64][4][2];
  const float* W = gat ? W1 : W0;
  const float* aa = gat ? a1 : a0;
  for (int idx = tid; idx < 4096; idx += 256){
    int i2 = idx >> 6, k = idx & 63;
    ctl[i2][k] = ct[(r0 + i2)*64 + k];
  }
  for (int idx = tid; idx < 4096; idx += 256){
    int k = idx >> 6, c = idx & 63;
    Wl[k][c] = W[k*64 + c];
  }
  if (tid < 64){ a1s[tid] = aa[tid]; a2s[tid] = aa[64 + tid]; }
  __syncthreads();
  float acc[16];
#pragma unroll
  for (int c = 0; c < 16; ++c) acc[c] = 0.f;
#pragma unroll 2
  for (int k = 0; k < 64; ++k){
    float v = ctl[ii][k];
    const float* wr = &Wl[k][cq*16];
#pragma unroll
    for (int c = 0; c < 16; ++c) acc[c] = fmaf(v, wr[c], acc[c]);
  }
  float p1 = 0.f, p2 = 0.f;
#pragma unroll
  for (int c = 0; c < 16; ++c){
    p1 = fmaf(acc[c], a1s[cq*16 + c], p1);
    p2 = fmaf(acc[c], a2s[cq*16 + c], p2);
  }
  red[ii][cq][0] = p1; red[ii][cq][1] = p2;
  float* o = WhABt + gat*16384;
#pragma unroll
  for (int c = 0; c < 16; ++c) o[(cq*16 + c)*256 + r0 + ii] = acc[c];
  __syncthreads();
  if (cq == 0){
    OF1[gat*256 + r0 + ii] = red[ii][0][0] + red[ii][1][0] + red[ii][2][0] + red[ii][3][0];
    OF2[gat*256 + r0 + ii] = red[ii][0][1] + red[ii][1][1] + red[ii][2][1] + red[ii][3][1];
  }
}

// ---- k8b: out/out1 attention. grid 8 = gat*4 + c-tile(16) ----
__global__ __launch_bounds__(256) void k8b(const float* __restrict__ WhABt,
                                           const float* __restrict__ OF1,
                                           const float* __restrict__ OF2,
                                           const unsigned* __restrict__ maskA,
                                           float* __restrict__ OUTT){
  const int gat = blockIdx.x >> 2, c0 = (blockIdx.x & 3) * 16;
  const int i = threadIdx.x;
  __shared__ float f2s[256];
  __shared__ float wt[64][36];
  const float f1 = OF1[gat*256 + i];
  f2s[i] = OF2[gat*256 + i];
  unsigned mw[8];
#pragma unroll
  for (int w = 0; w < 8; ++w) mw[w] = maskA[i*8 + w];
  __syncthreads();
  float m = -INFINITY;
  for (int w = 0; w < 8; ++w){
    const unsigned mk = mw[w];
#pragma unroll
    for (int bb = 0; bb < 32; ++bb){
      float e = f1 + f2s[(w<<5)+bb]; e = (e > 0.f) ? e : ALPHA*e;
      e = ((mk >> bb) & 1u) ? e : NEGV;
      m = fmaxf(m, e);
    }
  }
  float s = 0.f;
  for (int w = 0; w < 8; ++w){
    const unsigned mk = mw[w];
#pragma unroll
    for (int bb = 0; bb < 32; ++bb){
      float e = f1 + f2s[(w<<5)+bb]; e = (e > 0.f) ? e : ALPHA*e;
      e = ((mk >> bb) & 1u) ? e : NEGV;
      s += __expf(e - m);
    }
  }
  const float inv = 1.f / s;
  float acc[16];
#pragma unroll
  for (int c = 0; c < 16; ++c) acc[c] = 0.f;
  for (int jt = 0; jt < 4; ++jt){
    __syncthreads();
    for (int idx = i; idx < 1024; idx += 256){
      int cc = idx >> 6, jj = idx & 63;
      wt[jj][cc] = WhABt[gat*16384 + (c0+cc)*256 + (jt<<6) + jj];
    }
    __syncthreads();
    for (int jj = 0; jj < 64; ++jj){
      const int j = (jt<<6) + jj;
      float e = f1 + f2s[j]; e = (e > 0.f) ? e : ALPHA*e;
      e = ((mw[j>>5] >> (j & 31)) & 1u) ? e : NEGV;
      const float p = __expf(e - m) * inv;
      const float* wr = &wt[jj][0];
#pragma unroll
      for (int c = 0; c < 16; ++c) acc[c] = fmaf(p, wr[c], acc[c]);
    }
  }
#pragma unroll
  for (int c = 0; c < 16; ++c) OUTT[gat*16384 + (c0+c)*256 + i] = acc[c];
}

// ---- k8c: Wh2 (transposed) + F1B/F2B. grid 8 = 32-row chunks ----
__global__ __launch_bounds__(256) void k8c(const float* __restrict__ OUTT,
                                           const float* __restrict__ W2,
                                           const float* __restrict__ a2,
                                           float* __restrict__ Wh2,
                                           float* __restrict__ F1B,
                                           float* __restrict__ F2B){
  const int r0 = blockIdx.x * 32;
  const int tid = threadIdx.x;
  const int ii = tid & 31, cq = tid >> 5;      // 8 groups x 8 cols
  __shared__ float W2l[128][68];
  __shared__ float a1s[64], a2s[64];
  __shared__ float red[32][8][2];
  for (int idx = tid; idx < 8192; idx += 256){
    int k = idx >> 6, c = idx & 63;
    W2l[k][c] = W2[k*64 + c];
  }
  if (tid < 64){ a1s[tid] = a2[tid]; a2s[tid] = a2[64 + tid]; }
  __syncthreads();
  float acc[8];
#pragma unroll
  for (int c = 0; c < 8; ++c) acc[c] = 0.f;
#pragma unroll 2
  for (int k = 0; k < 128; ++k){
    float v = OUTT[(k >> 6)*16384 + (k & 63)*256 + r0 + ii];
    const float* wr = &W2l[k][cq*8];
#pragma unroll
    for (int c = 0; c < 8; ++c) acc[c] = fmaf(v, wr[c], acc[c]);
  }
  float p1 = 0.f, p2 = 0.f;
#pragma unroll
  for (int c = 0; c < 8; ++c){
    p1 = fmaf(acc[c], a1s[cq*8 + c], p1);
    p2 = fmaf(acc[c], a2s[cq*8 + c], p2);
  }
  red[ii][cq][0] = p1; red[ii][cq][1] = p2;
#pragma unroll
  for (int c = 0; c < 8; ++c) Wh2[(cq*8 + c)*256 + r0 + ii] = acc[c];
  __syncthreads();
  if (cq == 0){
    float s1 = 0.f, s2 = 0.f;
#pragma unroll
    for (int q = 0; q < 8; ++q){ s1 += red[ii][q][0]; s2 += red[ii][q][1]; }
    F1B[r0 + ii] = s1; F2B[r0 + ii] = s2;
  }
}

// ---- k8d: final GAT -> d_out. grid 4 = c-tiles(16) ----
__global__ __launch_bounds__(256) void k8d(const float* __restrict__ Wh2,
                                           const float* __restrict__ F1B,
                                           const float* __restrict__ F2B,
                                           const unsigned* __restrict__ maskA,
                                           float* __restrict__ dOut){
  const int c0 = blockIdx.x * 16;
  const int i = threadIdx.x;
  __shared__ float f2s[256];
  __shared__ float wt[64][36];
  const float f1 = F1B[i];
  f2s[i] = F2B[i];
  unsigned mw[8];
#pragma unroll
  for (int w = 0; w < 8; ++w) mw[w] = maskA[i*8 + w];
  __syncthreads();
  float m = -INFINITY;
  for (int w = 0; w < 8; ++w){
    const unsigned mk = mw[w];
#pragma unroll
    for (int bb = 0; bb < 32; ++bb){
      float e = f1 + f2s[(w<<5)+bb]; e = (e > 0.f) ? e : ALPHA*e;
      e = ((mk >> bb) & 1u) ? e : NEGV;
      m = fmaxf(m, e);
    }
  }
  float s = 0.f;
  for (int w = 0; w < 8; ++w){
    const unsigned mk = mw[w];
#pragma unroll
    for (int bb = 0; bb < 32; ++bb){
      float e = f1 + f2s[(w<<5)+bb]; e = (e > 0.f) ? e : ALPHA*e;
      e = ((mk >> bb) & 1u) ? e : NEGV;
      s += __expf(e - m);
    }
  }
  const float inv = 1.f / s;
  float acc[16];
#pragma unroll
  for (int c = 0; c < 16; ++c) acc[c] = 0.f;
  for (int jt = 0; jt < 4; ++jt){
    __syncthreads();
    for (int idx = i; idx < 1024; idx += 256){
      int cc = idx >> 6, jj = idx & 63;
      wt[jj][cc] = Wh2[(c0+cc)*256 + (jt<<6) + jj];
    }
    __syncthreads();
    for (int jj = 0; jj < 64; ++jj){
      const int j = (jt<<6) + jj;
      float e = f1 + f2s[j]; e = (e > 0.f) ? e : ALPHA*e;
      e = ((mw[j>>5] >> (j & 31)) & 1u) ? e : NEGV;
      const float p = __expf(e - m) * inv;
      const float* wr = &wt[jj][0];
#pragma unroll
      for (int c = 0; c < 16; ++c) acc[c] = fmaf(p, wr[c], acc[c]);
    }
  }
#pragma unroll
  for (int c = 0; c < 16; ++c) dOut[i*64 + c0 + c] = acc[c];
}

extern "C" void kernel_launch(void* const* d_in, const int* in_sizes, int n_in,
                              void* d_out, int out_size, void* d_ws, size_t ws_size,
                              hipStream_t stream){
  (void)in_sizes; (void)n_in; (void)out_size; (void)ws_size;
  const float* x     = (const float*)d_in[0];
  const float* Fadj  = (const float*)d_in[1];
  const float* Tadj  = (const float*)d_in[2];
  const float* adj   = (const float*)d_in[3];
  const float* Hpre  = (const float*)d_in[4];
  const float* FattW = (const float*)d_in[5];
  const float* Fatta = (const float*)d_in[6];
  const float* TattW = (const float*)d_in[7];
  const float* Tatta = (const float*)d_in[8];
  const float* Wih0  = (const float*)d_in[9];
  const float* Whh0  = (const float*)d_in[10];
  const float* bih0  = (const float*)d_in[11];
  const float* bhh0  = (const float*)d_in[12];
  const float* Wih1  = (const float*)d_in[13];
  const float* Whh1  = (const float*)d_in[14];
  const float* bih1  = (const float*)d_in[15];
  const float* bhh1  = (const float*)d_in[16];
  const float* fc1w  = (const float*)d_in[17];
  const float* fc1b  = (const float*)d_in[18];
  const float* fc2w  = (const float*)d_in[19];
  const float* fc2b  = (const float*)d_in[20];
  const float* fc3w  = (const float*)d_in[21];
  const float* fc3b  = (const float*)d_in[22];
  const float* oW    = (const float*)d_in[23];
  const float* oa    = (const float*)d_in[24];
  const float* o1W   = (const float*)d_in[25];
  const float* o1a   = (const float*)d_in[26];
  const float* o2W   = (const float*)d_in[27];
  const float* o2a   = (const float*)d_in[28];
  float* out = (float*)d_out;

  float* ws = (float*)d_ws;
  float* R0 = ws;
  float* R1 = ws + 4194304;
  float* R2 = ws + 8388608;
  unsigned* maskT = (unsigned*)R2;             // 524288 words
  float* Tf1p = R2 + 524288;                   // 2 x 65536
  float* Tf2p = R2 + 655360;                   // 2 x 65536
  unsigned* maskA = (unsigned*)(ws + 12582912);// 2048 words
  float* WhTt = R0;
  float* WhF  = R0;
  float* Gi0  = R0;
  float* TatT = R1;
  float* Fat  = R2;
  float* ctb   = R1;                           // tail (TatT dead after k5)
  float* WhABt = R1 + 16384;
  float* OF1   = R1 + 49152;
  float* OF2   = R1 + 49664;
  float* OUTT  = R1 + 50176;
  float* WH2   = R1 + 82944;
  float* F1B   = R1 + 99328;
  float* F2B   = R1 + 99584;

  k_mask<<<1024, 256, 0, stream>>>(Tadj, maskT, 16777216);
  k_mask<<<32, 256, 0, stream>>>(adj, maskA, 65536);
  k3_wht<<<512, 256, 0, stream>>>(x, TattW, Tatta, WhTt, Tf1p, Tf2p);
  k4_tat<<<512, 256, 0, stream>>>(WhTt, Tf1p, Tf2p, maskT, TatT);
  k1_whf<<<256, 512, 0, stream>>>(x, FattW, WhF);
  k2_fat<<<256, 512, 0, stream>>>(WhF, Fatta, Fadj, Fat);
  k5_gi0<<<256, 512, 0, stream>>>(Fat, TatT, x, Wih0, Gi0);
  k6_gru<<<256, 64, 0, stream>>>(Gi0, Hpre, Whh0, bih0, bhh0, Wih1, Whh1, bih1, bhh1,
                                 fc1w, fc1b, fc2w, fc2b, fc3w, fc3b, ctb, out);
  k8a<<<8, 256, 0, stream>>>(ctb, oW, oa, o1W, o1a, WhABt, OF1, OF2);
  k8b<<<8, 256, 0, stream>>>(WhABt, OF1, OF2, maskA, OUTT);
  k8c<<<8, 256, 0, stream>>>(OUTT, o2W, o2a, WH2, F1B, F2B);
  k8d<<<4, 256, 0, stream>>>(WH2, F1B, F2B, maskA, out);
}

// Round 5
// 860.572 us; speedup vs baseline: 1.1726x; 1.0261x over previous
//
#include <hip/hip_runtime.h>
#include <hip/hip_bf16.h>

__device__ __forceinline__ float sigf(float x){ return 1.f/(1.f+__expf(-x)); }

#define ALPHA 0.2f
#define NEGV  -9e15f

// N=256 nodes, S=64 sensors, W=256 window, H=32 hidden. All fp32.

// ---- k_mask: pack adjacency fp32 (0/1) -> bitmask via wave ballot ----
__global__ __launch_bounds__(256) void k_mask(const float* __restrict__ src,
                                              unsigned* __restrict__ dst, int nelem){
  const int stride = gridDim.x * blockDim.x;
  const int lane = threadIdx.x & 63;
  for (int e = blockIdx.x*blockDim.x + threadIdx.x; e < nelem; e += stride){
    unsigned long long m = __ballot(src[e] > 0.f);
    if (lane == 0)       dst[e >> 5] = (unsigned)m;
    else if (lane == 32) dst[e >> 5] = (unsigned)(m >> 32);
  }
}

// ---- k3: Wh_T (transposed store) + Tf1/Tf2 partials. grid 512 = n*2 + c-half ----
__global__ __launch_bounds__(256) void k3_wht(const float* __restrict__ x,
                                              const float* __restrict__ TW,
                                              const float* __restrict__ Ta,
                                              float* __restrict__ WhTt,
                                              float* __restrict__ Tf1p,
                                              float* __restrict__ Tf2p){
  const int n = blockIdx.x >> 1, ch = blockIdx.x & 1, c0 = ch*32;
  const int tid = threadIdx.x;
  __shared__ float Wm[64][36];
  __shared__ float as1[32], as2[32];
  for (int idx = tid; idx < 2048; idx += 256){
    int k = idx >> 5, cc = idx & 31;
    Wm[k][cc] = TW[n*4096 + k*64 + c0 + cc];
  }
  if (tid < 32){ as1[tid] = Ta[n*128 + c0 + tid]; as2[tid] = Ta[n*128 + 64 + c0 + tid]; }
  __syncthreads();
  const int i = tid;
  const float* xn = x + n*16384;
  float acc[32];
#pragma unroll
  for (int c = 0; c < 32; ++c) acc[c] = 0.f;
#pragma unroll 2
  for (int k = 0; k < 64; ++k){
    float xv = xn[k*256 + i];                  // coalesced
    const float* wr = &Wm[k][0];               // broadcast b128
#pragma unroll
    for (int c = 0; c < 32; ++c) acc[c] = fmaf(xv, wr[c], acc[c]);
  }
  float f1 = 0.f, f2 = 0.f;
#pragma unroll
  for (int c = 0; c < 32; ++c){ f1 = fmaf(acc[c], as1[c], f1); f2 = fmaf(acc[c], as2[c], f2); }
  Tf1p[ch*65536 + n*256 + i] = f1;
  Tf2p[ch*65536 + n*256 + i] = f2;
  float* o = WhTt + n*16384;
#pragma unroll
  for (int c = 0; c < 32; ++c) o[(c0+c)*256 + i] = acc[c];
}

// ---- k4: time-GAT attention. grid 512 = n*2 + c-half, thread = window row i ----
__global__ __launch_bounds__(256) void k4_tat(const float* __restrict__ WhTt,
                                              const float* __restrict__ Tf1p,
                                              const float* __restrict__ Tf2p,
                                              const unsigned* __restrict__ maskT,
                                              float* __restrict__ TatT){
  const int n = blockIdx.x >> 1, ch = blockIdx.x & 1, c0 = ch*32;
  const int i = threadIdx.x;
  __shared__ float f2s[256];
  __shared__ float wt[64][36];
  const float f1 = Tf1p[n*256 + i] + Tf1p[65536 + n*256 + i];
  f2s[i] = Tf2p[n*256 + i] + Tf2p[65536 + n*256 + i];
  unsigned mw[8];
#pragma unroll
  for (int w = 0; w < 8; ++w) mw[w] = maskT[n*2048 + i*8 + w];
  __syncthreads();
  float m = -INFINITY;
  for (int w = 0; w < 8; ++w){
    const unsigned mk = mw[w];
#pragma unroll
    for (int bb = 0; bb < 32; ++bb){
      float e = f1 + f2s[(w<<5)+bb]; e = (e > 0.f) ? e : ALPHA*e;
      e = ((mk >> bb) & 1u) ? e : NEGV;
      m = fmaxf(m, e);
    }
  }
  float s = 0.f;
  for (int w = 0; w < 8; ++w){
    const unsigned mk = mw[w];
#pragma unroll
    for (int bb = 0; bb < 32; ++bb){
      float e = f1 + f2s[(w<<5)+bb]; e = (e > 0.f) ? e : ALPHA*e;
      e = ((mk >> bb) & 1u) ? e : NEGV;
      s += __expf(e - m);
    }
  }
  const float inv = 1.f / s;
  float acc[32];
#pragma unroll
  for (int c = 0; c < 32; ++c) acc[c] = 0.f;
  for (int jt = 0; jt < 4; ++jt){
    __syncthreads();
    for (int idx = i; idx < 2048; idx += 256){
      int cc = idx >> 6, jj = idx & 63;
      wt[jj][cc] = WhTt[n*16384 + (c0+cc)*256 + (jt<<6) + jj];   // coalesced
    }
    __syncthreads();
    for (int jj = 0; jj < 64; ++jj){
      const int j = (jt<<6) + jj;
      float e = f1 + f2s[j]; e = (e > 0.f) ? e : ALPHA*e;
      e = ((mw[j>>5] >> (j & 31)) & 1u) ? e : NEGV;
      const float p = __expf(e - m) * inv;
      const float* wr = &wt[jj][0];            // broadcast b128
#pragma unroll
      for (int c = 0; c < 32; ++c) acc[c] = fmaf(p, wr[c], acc[c]);
    }
  }
  float* o = TatT + n*16384;
#pragma unroll
  for (int c = 0; c < 32; ++c) o[(c0+c)*256 + i] = acc[c];
}

// ---- k1: Wh_F = x @ Fatt_W. grid 256, block 512 (two k-halves, LDS reduce) ----
__global__ __launch_bounds__(512) void k1_whf(const float* __restrict__ x,
                                              const float* __restrict__ FW,
                                              float* __restrict__ WhF){
  const int n = blockIdx.x, tid = threadIdx.x;
  __shared__ float xt[256][64];                // 64 KB; rotated layout (bank-friendly)
  const float* xn = x + n*16384;
  for (int idx = tid; idx < 16384; idx += 512){
    int i = idx >> 8, k = idx & 255;
    xt[k][(i + (k & 60)) & 63] = xn[idx];      // coalesced read
  }
  __syncthreads();
  const int c = tid & 255, kg = tid >> 8;
  const float* Wn = FW + (size_t)n*65536;
  float acc[64];
#pragma unroll
  for (int i = 0; i < 64; ++i) acc[i] = 0.f;
  const int kbeg = kg*128, kend = kbeg + 128;
#pragma unroll 2
  for (int k = kbeg; k < kend; ++k){
    float w = Wn[k*256 + c];                   // coalesced
    const float4* xr = (const float4*)&xt[k][0];
    const int r4 = (k >> 2) & 15;
#pragma unroll
    for (int g = 0; g < 16; ++g){
      float4 v = xr[(g + r4) & 15];            // broadcast b128, uniform rotated index
      acc[4*g+0] = fmaf(v.x, w, acc[4*g+0]);
      acc[4*g+1] = fmaf(v.y, w, acc[4*g+1]);
      acc[4*g+2] = fmaf(v.z, w, acc[4*g+2]);
      acc[4*g+3] = fmaf(v.w, w, acc[4*g+3]);
    }
  }
  __syncthreads();
  float* buf = &xt[0][0];                      // reuse LDS as 64x256 reduce buffer
  if (kg == 1){
#pragma unroll
    for (int i = 0; i < 64; ++i) buf[i*256 + c] = acc[i];
  }
  __syncthreads();
  if (kg == 0){
    float* o = WhF + n*16384;
#pragma unroll
    for (int i = 0; i < 64; ++i) o[i*256 + c] = acc[i] + buf[i*256 + c];
  }
}

// ---- k2: feature-GAT softmax + Fat = att @ Wh. grid 256, block 512 (i-split) ----
__global__ __launch_bounds__(512) void k2_fat(const float* __restrict__ WhF,
                                              const float* __restrict__ Fa,
                                              const float* __restrict__ Fadj,
                                              float* __restrict__ Fat){
  const int n = blockIdx.x, tid = threadIdx.x;
  __shared__ float attT[64][68];               // attT[j][i]
  __shared__ float f1s[64], f2s[64];
  __shared__ float part[64][8][2];
  const float* Wh = WhF + n*16384;
  { // f1/f2: thread (i=tid>>3, q=tid&7) partial over 32 cols
    int i = tid >> 3, q = tid & 7;
    const float* an = Fa + n*512;
    float p1 = 0.f, p2 = 0.f;
    for (int cc = 0; cc < 32; ++cc){
      int c2 = q*32 + cc;
      float w = Wh[i*256 + c2];
      p1 = fmaf(w, an[c2], p1);
      p2 = fmaf(w, an[256 + c2], p2);
    }
    part[i][q][0] = p1; part[i][q][1] = p2;
  }
  __syncthreads();
  if (tid < 64){
    float s1 = 0.f, s2 = 0.f;
#pragma unroll
    for (int q = 0; q < 8; ++q){ s1 += part[tid][q][0]; s2 += part[tid][q][1]; }
    f1s[tid] = s1; f2s[tid] = s2;
  }
  __syncthreads();
  if (tid < 64){                               // masked softmax row -> attT column
    const int r = tid;
    const float f1 = f1s[r];
    const float* adjr = Fadj + n*4096 + r*64;
    unsigned m0 = 0, m1 = 0;
#pragma unroll
    for (int j = 0; j < 32; ++j) if (adjr[j] > 0.f) m0 |= (1u << j);
#pragma unroll
    for (int j = 0; j < 32; ++j) if (adjr[32+j] > 0.f) m1 |= (1u << j);
    float m = -INFINITY;
#pragma unroll
    for (int j = 0; j < 64; ++j){
      float e = f1 + f2s[j]; e = (e > 0.f) ? e : ALPHA*e;
      unsigned bit = (j < 32) ? ((m0 >> j) & 1u) : ((m1 >> (j-32)) & 1u);
      e = bit ? e : NEGV;
      m = fmaxf(m, e);
    }
    float s = 0.f;
#pragma unroll
    for (int j = 0; j < 64; ++j){
      float e = f1 + f2s[j]; e = (e > 0.f) ? e : ALPHA*e;
      unsigned bit = (j < 32) ? ((m0 >> j) & 1u) : ((m1 >> (j-32)) & 1u);
      e = bit ? e : NEGV;
      s += __expf(e - m);
    }
    const float inv = 1.f / s;
#pragma unroll
    for (int j = 0; j < 64; ++j){
      float e = f1 + f2s[j]; e = (e > 0.f) ? e : ALPHA*e;
      unsigned bit = (j < 32) ? ((m0 >> j) & 1u) : ((m1 >> (j-32)) & 1u);
      e = bit ? e : NEGV;
      attT[j][r] = __expf(e - m) * inv;
    }
  }
  __syncthreads();
  const int c = tid & 255, ih = tid >> 8;      // ih: 32-row half of output
  float acc[32];
#pragma unroll
  for (int i = 0; i < 32; ++i) acc[i] = 0.f;
#pragma unroll 2
  for (int j = 0; j < 64; ++j){
    float w = Wh[j*256 + c];                   // coalesced, L2-hot
    const float* ar = &attT[j][ih*32];         // broadcast b128 (16B-aligned)
#pragma unroll
    for (int i = 0; i < 32; ++i) acc[i] = fmaf(ar[i], w, acc[i]);
  }
  float* o = Fat + n*16384;
#pragma unroll
  for (int i = 0; i < 32; ++i) o[(ih*32 + i)*256 + c] = acc[i];
}

// ---- k5: Gi0 = cat_at @ Wih0^T. grid 256, block 512 (two k-halves, LDS reduce) ----
__global__ __launch_bounds__(512) void k5_gi0(const float* __restrict__ Fat,
                                              const float* __restrict__ TatT,
                                              const float* __restrict__ x,
                                              const float* __restrict__ Wih0,
                                              float* __restrict__ Gi0){
  const int n = blockIdx.x, tid = threadIdx.x;
  __shared__ float wl[2][96][36];              // 27648 B
  __shared__ float cl[2][64][36];              // 18432 B
  const int kg = tid >> 8, lt = tid & 255;
  const int b = lt >> 5, a = lt & 31;          // b: 12-gate group, a: t-lane
  float acc[12][2];
#pragma unroll
  for (int gi = 0; gi < 12; ++gi){ acc[gi][0] = 0.f; acc[gi][1] = 0.f; }
  for (int r = 0; r < 12; ++r){
    __syncthreads();
    const int kt = r*2 + kg;                   // 32-wide k tile, 0..23
    const int k0 = kt * 32;
    const float* Wn = Wih0 + (size_t)n*73728 + k0;
    for (int idx = lt; idx < 3072; idx += 256){
      int g = idx >> 5, kk = idx & 31;
      wl[kg][g][kk] = Wn[g*768 + kk];
    }
    const int seg = kt >> 3, ko = (kt & 7) * 32;   // 0:Fat 1:Tat^T 2:x
    const float* sp = (seg == 0) ? (Fat + n*16384 + ko)
                    : (seg == 1) ? (TatT + n*16384 + ko)
                                 : (x + n*16384 + ko);
    for (int idx = lt; idx < 2048; idx += 256){
      int t = idx >> 5, kk = idx & 31;
      cl[kg][t][kk] = sp[t*256 + kk];
    }
    __syncthreads();
    for (int kk = 0; kk < 32; kk += 4){
      const float4 c0v = *(const float4*)&cl[kg][a][kk];
      const float4 c1v = *(const float4*)&cl[kg][a + 32][kk];
#pragma unroll
      for (int gi = 0; gi < 12; ++gi){
        const float4 wv = *(const float4*)&wl[kg][b*12 + gi][kk];
        float a0 = acc[gi][0], a1v = acc[gi][1];
        a0  = fmaf(wv.x, c0v.x, a0);  a0  = fmaf(wv.y, c0v.y, a0);
        a0  = fmaf(wv.z, c0v.z, a0);  a0  = fmaf(wv.w, c0v.w, a0);
        a1v = fmaf(wv.x, c1v.x, a1v); a1v = fmaf(wv.y, c1v.y, a1v);
        a1v = fmaf(wv.z, c1v.z, a1v); a1v = fmaf(wv.w, c1v.w, a1v);
        acc[gi][0] = a0; acc[gi][1] = a1v;
      }
    }
  }
  __syncthreads();
  float* buf = &wl[0][0][0];                   // 6144 floats needed, fits in wl
  if (kg == 1){
#pragma unroll
    for (int gi = 0; gi < 12; ++gi){
      buf[lt*24 + gi*2]     = acc[gi][0];
      buf[lt*24 + gi*2 + 1] = acc[gi][1];
    }
  }
  __syncthreads();
  if (kg == 0){
    float* o = Gi0 + n*6144;
#pragma unroll
    for (int gi = 0; gi < 12; ++gi){
      o[a*96 + b*12 + gi]        = acc[gi][0] + buf[lt*24 + gi*2];
      o[(a + 32)*96 + b*12 + gi] = acc[gi][1] + buf[lt*24 + gi*2 + 1];
    }
  }
}

// ---- k6: 2-layer GRU (64 steps), spill-free distributed-register design ----
// One wave per node. Lane l = (g2 = l&31, hh = l>>5). Lane holds the hh-half
// (16 cols) of its 3 gate rows (r=g2, z=32+g2, n=64+g2) in each recurrent
// matrix: 9x16 = 144 weight VGPRs, no duplication. Partial dots completed by
// one shfl_xor(32) per gate; h state via 32-float LDS (1-wave barrier ~free).
__global__ __launch_bounds__(64) void k6_gru(const float* __restrict__ Gi0,
                                             const float* __restrict__ Hpre,
                                             const float* __restrict__ Whh0,
                                             const float* __restrict__ bih0,
                                             const float* __restrict__ bhh0,
                                             const float* __restrict__ Wih1,
                                             const float* __restrict__ Whh1,
                                             const float* __restrict__ bih1,
                                             const float* __restrict__ bhh1,
                                             const float* __restrict__ fc1w,
                                             const float* __restrict__ fc1b,
                                             const float* __restrict__ fc2w,
                                             const float* __restrict__ fc2b,
                                             const float* __restrict__ fc3w,
                                             const float* __restrict__ fc3b,
                                             float* __restrict__ ct,
                                             float* __restrict__ dout){
  const int n = blockIdx.x, l = threadIdx.x;
  const int g2 = l & 31, hh = l >> 5, co = hh * 16;
  __shared__ float h0sh[32], h1sh[32];
  __shared__ float hist[64][33];
  __shared__ float Wst[32][33];
  __shared__ float b1s[32], b2s[32], w3s[32];
  // ---- weight slices (144 VGPRs) ----
  float w0r[16], w0z[16], w0n[16];
  float wi1r[16], wi1z[16], wi1n[16];
  float wh1r[16], wh1z[16], wh1n[16];
  {
    const float* W0  = Whh0 + n*3072;
    const float* Wi1 = Wih1 + n*3072;
    const float* Wh1 = Whh1 + n*3072;
#pragma unroll
    for (int q = 0; q < 4; ++q){
      float4 v;
      v = *(const float4*)(W0 + g2*32 + co + 4*q);        w0r[4*q]=v.x; w0r[4*q+1]=v.y; w0r[4*q+2]=v.z; w0r[4*q+3]=v.w;
      v = *(const float4*)(W0 + (32+g2)*32 + co + 4*q);   w0z[4*q]=v.x; w0z[4*q+1]=v.y; w0z[4*q+2]=v.z; w0z[4*q+3]=v.w;
      v = *(const float4*)(W0 + (64+g2)*32 + co + 4*q);   w0n[4*q]=v.x; w0n[4*q+1]=v.y; w0n[4*q+2]=v.z; w0n[4*q+3]=v.w;
      v = *(const float4*)(Wi1 + g2*32 + co + 4*q);       wi1r[4*q]=v.x; wi1r[4*q+1]=v.y; wi1r[4*q+2]=v.z; wi1r[4*q+3]=v.w;
      v = *(const float4*)(Wi1 + (32+g2)*32 + co + 4*q);  wi1z[4*q]=v.x; wi1z[4*q+1]=v.y; wi1z[4*q+2]=v.z; wi1z[4*q+3]=v.w;
      v = *(const float4*)(Wi1 + (64+g2)*32 + co + 4*q);  wi1n[4*q]=v.x; wi1n[4*q+1]=v.y; wi1n[4*q+2]=v.z; wi1n[4*q+3]=v.w;
      v = *(const float4*)(Wh1 + g2*32 + co + 4*q);       wh1r[4*q]=v.x; wh1r[4*q+1]=v.y; wh1r[4*q+2]=v.z; wh1r[4*q+3]=v.w;
      v = *(const float4*)(Wh1 + (32+g2)*32 + co + 4*q);  wh1z[4*q]=v.x; wh1z[4*q+1]=v.y; wh1z[4*q+2]=v.z; wh1z[4*q+3]=v.w;
      v = *(const float4*)(Wh1 + (64+g2)*32 + co + 4*q);  wh1n[4*q]=v.x; wh1n[4*q+1]=v.y; wh1n[4*q+2]=v.z; wh1n[4*q+3]=v.w;
    }
  }
  const float bi0r = bih0[n*96 + g2], bi0z = bih0[n*96 + 32 + g2], bi0n = bih0[n*96 + 64 + g2];
  const float bh0r = bhh0[n*96 + g2], bh0z = bhh0[n*96 + 32 + g2], bh0n = bhh0[n*96 + 64 + g2];
  const float bi1r = bih1[n*96 + g2], bi1z = bih1[n*96 + 32 + g2], bi1n = bih1[n*96 + 64 + g2];
  const float bh1r = bhh1[n*96 + g2], bh1z = bhh1[n*96 + 32 + g2], bh1n = bhh1[n*96 + 64 + g2];
  // ---- state ----
  float h0own = Hpre[n*32 + g2];
  float h1own = Hpre[8192 + n*32 + g2];
  if (l < 32){ h0sh[l] = h0own; h1sh[l] = h1own; }
  __syncthreads();
  float h0s[16], h1s[16];
#pragma unroll
  for (int q = 0; q < 4; ++q){
    float4 v0 = *(const float4*)&h0sh[co + 4*q];
    float4 v1 = *(const float4*)&h1sh[co + 4*q];
    h0s[4*q]=v0.x; h0s[4*q+1]=v0.y; h0s[4*q+2]=v0.z; h0s[4*q+3]=v0.w;
    h1s[4*q]=v1.x; h1s[4*q+1]=v1.y; h1s[4*q+2]=v1.z; h1s[4*q+3]=v1.w;
  }
  const float* gin = Gi0 + n*6144;
  float gir = gin[g2], giz = gin[32 + g2], ginn = gin[64 + g2];
  for (int t = 0; t < 64; ++t){
    float gir_n = 0.f, giz_n = 0.f, ginn_n = 0.f;
    if (t < 63){
      const float* gp = gin + (t+1)*96;
      gir_n = gp[g2]; giz_n = gp[32 + g2]; ginn_n = gp[64 + g2];
    }
    // ---- layer 0 ----
    float pr = 0.f, pz = 0.f, pn = 0.f;
#pragma unroll
    for (int j = 0; j < 16; ++j){
      pr = fmaf(w0r[j], h0s[j], pr);
      pz = fmaf(w0z[j], h0s[j], pz);
      pn = fmaf(w0n[j], h0s[j], pn);
    }
    pr += __shfl_xor(pr, 32);
    pz += __shfl_xor(pz, 32);
    pn += __shfl_xor(pn, 32);
    float r = sigf(gir + bi0r + pr + bh0r);
    float z = sigf(giz + bi0z + pz + bh0z);
    float nn = tanhf(ginn + bi0n + r*(pn + bh0n));
    float h0new = (1.f - z)*nn + z*h0own;
    h0own = h0new;
    if (l < 32) h0sh[g2] = h0new;
    __syncthreads();
#pragma unroll
    for (int q = 0; q < 4; ++q){
      float4 v0 = *(const float4*)&h0sh[co + 4*q];
      h0s[4*q]=v0.x; h0s[4*q+1]=v0.y; h0s[4*q+2]=v0.z; h0s[4*q+3]=v0.w;
    }
    // ---- layer 1 ----
    float qr = 0.f, qz = 0.f, qn = 0.f, sr = 0.f, sz = 0.f, sn = 0.f;
#pragma unroll
    for (int j = 0; j < 16; ++j){
      qr = fmaf(wi1r[j], h0s[j], qr);  sr = fmaf(wh1r[j], h1s[j], sr);
      qz = fmaf(wi1z[j], h0s[j], qz);  sz = fmaf(wh1z[j], h1s[j], sz);
      qn = fmaf(wi1n[j], h0s[j], qn);  sn = fmaf(wh1n[j], h1s[j], sn);
    }
    float vr = qr + sr; vr += __shfl_xor(vr, 32);
    float vz = qz + sz; vz += __shfl_xor(vz, 32);
    qn += __shfl_xor(qn, 32);
    sn += __shfl_xor(sn, 32);
    float r1 = sigf(vr + bi1r + bh1r);
    float z1 = sigf(vz + bi1z + bh1z);
    float n1 = tanhf(qn + bi1n + r1*(sn + bh1n));
    float h1new = (1.f - z1)*n1 + z1*h1own;
    h1own = h1new;
    if (l < 32){ h1sh[g2] = h1new; hist[t][g2] = h1new; }
    __syncthreads();
#pragma unroll
    for (int q = 0; q < 4; ++q){
      float4 v1 = *(const float4*)&h1sh[co + 4*q];
      h1s[4*q]=v1.x; h1s[4*q+1]=v1.y; h1s[4*q+2]=v1.z; h1s[4*q+3]=v1.w;
    }
    gir = gir_n; giz = giz_n; ginn = ginn_n;
  }
  if (l < 32){
    dout[16384 + n*32 + l]        = h0own;            // cat_H[0]
    dout[16384 + 8192 + n*32 + l] = h1own;            // cat_H[1]
  }
  // ---- fused FC head: lane = sensor s (64) ----
  if (l < 32){
    b1s[l] = fc1b[n*32 + l];
    b2s[l] = fc2b[n*32 + l];
    w3s[l] = fc3w[n*32 + l];
  }
  for (int idx = l; idx < 1024; idx += 64) Wst[idx>>5][idx&31] = fc1w[n*1024 + idx];
  __syncthreads();
  float hr[32];
#pragma unroll
  for (int k = 0; k < 32; ++k) hr[k] = hist[l][k];
  float r1a[32];
#pragma unroll
  for (int k = 0; k < 32; ++k){
    float a0=0.f,a1=0.f,a2=0.f,a3=0.f;
#pragma unroll
    for (int q = 0; q < 32; q += 4){
      a0 = fmaf(hr[q],   Wst[k][q],   a0);
      a1 = fmaf(hr[q+1], Wst[k][q+1], a1);
      a2 = fmaf(hr[q+2], Wst[k][q+2], a2);
      a3 = fmaf(hr[q+3], Wst[k][q+3], a3);
    }
    float v = b1s[k] + ((a0+a1)+(a2+a3));
    r1a[k] = v > 0.f ? v : 0.f;
  }
  __syncthreads();
  for (int idx = l; idx < 1024; idx += 64) Wst[idx>>5][idx&31] = fc2w[n*1024 + idx];
  __syncthreads();
  float r2a[32];
#pragma unroll
  for (int k = 0; k < 32; ++k){
    float a0=0.f,a1=0.f,a2=0.f,a3=0.f;
#pragma unroll
    for (int q = 0; q < 32; q += 4){
      a0 = fmaf(r1a[q],   Wst[k][q],   a0);
      a1 = fmaf(r1a[q+1], Wst[k][q+1], a1);
      a2 = fmaf(r1a[q+2], Wst[k][q+2], a2);
      a3 = fmaf(r1a[q+3], Wst[k][q+3], a3);
    }
    float v = b2s[k] + ((a0+a1)+(a2+a3));
    r2a[k] = v > 0.f ? v : 0.f;
  }
  float v = fc3b[n];
#pragma unroll
  for (int k = 0; k < 32; ++k) v = fmaf(r2a[k], w3s[k], v);
  ct[n*64 + l] = v;
}

// ---- k8a: Wh (transposed) + f1/f2 for out & out1. grid 8 = gat*4 + row-quarter ----
__global__ __launch_bounds__(256) void k8a(const float* __restrict__ ct,
                                           const float* __restrict__ W0,
                                           const float* __restrict__ a0,
                                           const float* __restrict__ W1,
                                           const float* __restrict__ a1,
                                           float* __restrict__ WhABt,
                                           float* __restrict__ OF1,
                                           float* __restrict__ OF2){
  const int gat = blockIdx.x >> 2, rq = blockIdx.x & 3, r0 = rq*64;
  const int tid = threadIdx.x;
  const int ii = tid & 63, cq = tid >> 6;
  __shared__ float ctl[64][65];
  __shared__ float Wl[64][68];
  __shared__ float a1s[64], a2s[64];
  __shared__ float red[64][4][2];
  const float* W = gat ? W1 : W0;
  const float* aa = gat ? a1 : a0;
  for (int idx = tid; idx < 4096; idx += 256){
    int i2 = idx >> 6, k = idx & 63;
    ctl[i2][k] = ct[(r0 + i2)*64 + k];
  }
  for (int idx = tid; idx < 4096; idx += 256){
    int k = idx >> 6, c = idx & 63;
    Wl[k][c] = W[k*64 + c];
  }
  if (tid < 64){ a1s[tid] = aa[tid]; a2s[tid] = aa[64 + tid]; }
  __syncthreads();
  float acc[16];
#pragma unroll
  for (int c = 0; c < 16; ++c) acc[c] = 0.f;
#pragma unroll 2
  for (int k = 0; k < 64; ++k){
    float v = ctl[ii][k];
    const float* wr = &Wl[k][cq*16];
#pragma unroll
    for (int c = 0; c < 16; ++c) acc[c] = fmaf(v, wr[c], acc[c]);
  }
  float p1 = 0.f, p2 = 0.f;
#pragma unroll
  for (int c = 0; c < 16; ++c){
    p1 = fmaf(acc[c], a1s[cq*16 + c], p1);
    p2 = fmaf(acc[c], a2s[cq*16 + c], p2);
  }
  red[ii][cq][0] = p1; red[ii][cq][1] = p2;
  float* o = WhABt + gat*16384;
#pragma unroll
  for (int c = 0; c < 16; ++c) o[(cq*16 + c)*256 + r0 + ii] = acc[c];
  __syncthreads();
  if (cq == 0){
    OF1[gat*256 + r0 + ii] = red[ii][0][0] + red[ii][1][0] + red[ii][2][0] + red[ii][3][0];
    OF2[gat*256 + r0 + ii] = red[ii][0][1] + red[ii][1][1] + red[ii][2][1] + red[ii][3][1];
  }
}

// ---- k8b: out/out1 attention. grid 8 = gat*4 + c-tile(16) ----
__global__ __launch_bounds__(256) void k8b(const float* __restrict__ WhABt,
                                           const float* __restrict__ OF1,
                                           const float* __restrict__ OF2,
                                           const unsigned* __restrict__ maskA,
                                           float* __restrict__ OUTT){
  const int gat = blockIdx.x >> 2, c0 = (blockIdx.x & 3) * 16;
  const int i = threadIdx.x;
  __shared__ float f2s[256];
  __shared__ float wt[64][36];
  const float f1 = OF1[gat*256 + i];
  f2s[i] = OF2[gat*256 + i];
  unsigned mw[8];
#pragma unroll
  for (int w = 0; w < 8; ++w) mw[w] = maskA[i*8 + w];
  __syncthreads();
  float m = -INFINITY;
  for (int w = 0; w < 8; ++w){
    const unsigned mk = mw[w];
#pragma unroll
    for (int bb = 0; bb < 32; ++bb){
      float e = f1 + f2s[(w<<5)+bb]; e = (e > 0.f) ? e : ALPHA*e;
      e = ((mk >> bb) & 1u) ? e : NEGV;
      m = fmaxf(m, e);
    }
  }
  float s = 0.f;
  for (int w = 0; w < 8; ++w){
    const unsigned mk = mw[w];
#pragma unroll
    for (int bb = 0; bb < 32; ++bb){
      float e = f1 + f2s[(w<<5)+bb]; e = (e > 0.f) ? e : ALPHA*e;
      e = ((mk >> bb) & 1u) ? e : NEGV;
      s += __expf(e - m);
    }
  }
  const float inv = 1.f / s;
  float acc[16];
#pragma unroll
  for (int c = 0; c < 16; ++c) acc[c] = 0.f;
  for (int jt = 0; jt < 4; ++jt){
    __syncthreads();
    for (int idx = i; idx < 1024; idx += 256){
      int cc = idx >> 6, jj = idx & 63;
      wt[jj][cc] = WhABt[gat*16384 + (c0+cc)*256 + (jt<<6) + jj];
    }
    __syncthreads();
    for (int jj = 0; jj < 64; ++jj){
      const int j = (jt<<6) + jj;
      float e = f1 + f2s[j]; e = (e > 0.f) ? e : ALPHA*e;
      e = ((mw[j>>5] >> (j & 31)) & 1u) ? e : NEGV;
      const float p = __expf(e - m) * inv;
      const float* wr = &wt[jj][0];
#pragma unroll
      for (int c = 0; c < 16; ++c) acc[c] = fmaf(p, wr[c], acc[c]);
    }
  }
#pragma unroll
  for (int c = 0; c < 16; ++c) OUTT[gat*16384 + (c0+c)*256 + i] = acc[c];
}

// ---- k8c: Wh2 (transposed) + F1B/F2B. grid 8 = 32-row chunks ----
__global__ __launch_bounds__(256) void k8c(const float* __restrict__ OUTT,
                                           const float* __restrict__ W2,
                                           const float* __restrict__ a2,
                                           float* __restrict__ Wh2,
                                           float* __restrict__ F1B,
                                           float* __restrict__ F2B){
  const int r0 = blockIdx.x * 32;
  const int tid = threadIdx.x;
  const int ii = tid & 31, cq = tid >> 5;      // 8 groups x 8 cols
  __shared__ float W2l[128][68];
  __shared__ float a1s[64], a2s[64];
  __shared__ float red[32][8][2];
  for (int idx = tid; idx < 8192; idx += 256){
    int k = idx >> 6, c = idx & 63;
    W2l[k][c] = W2[k*64 + c];
  }
  if (tid < 64){ a1s[tid] = a2[tid]; a2s[tid] = a2[64 + tid]; }
  __syncthreads();
  float acc[8];
#pragma unroll
  for (int c = 0; c < 8; ++c) acc[c] = 0.f;
#pragma unroll 2
  for (int k = 0; k < 128; ++k){
    float v = OUTT[(k >> 6)*16384 + (k & 63)*256 + r0 + ii];
    const float* wr = &W2l[k][cq*8];
#pragma unroll
    for (int c = 0; c < 8; ++c) acc[c] = fmaf(v, wr[c], acc[c]);
  }
  float p1 = 0.f, p2 = 0.f;
#pragma unroll
  for (int c = 0; c < 8; ++c){
    p1 = fmaf(acc[c], a1s[cq*8 + c], p1);
    p2 = fmaf(acc[c], a2s[cq*8 + c], p2);
  }
  red[ii][cq][0] = p1; red[ii][cq][1] = p2;
#pragma unroll
  for (int c = 0; c < 8; ++c) Wh2[(cq*8 + c)*256 + r0 + ii] = acc[c];
  __syncthreads();
  if (cq == 0){
    float s1 = 0.f, s2 = 0.f;
#pragma unroll
    for (int q = 0; q < 8; ++q){ s1 += red[ii][q][0]; s2 += red[ii][q][1]; }
    F1B[r0 + ii] = s1; F2B[r0 + ii] = s2;
  }
}

// ---- k8d: final GAT -> d_out. grid 4 = c-tiles(16) ----
__global__ __launch_bounds__(256) void k8d(const float* __restrict__ Wh2,
                                           const float* __restrict__ F1B,
                                           const float* __restrict__ F2B,
                                           const unsigned* __restrict__ maskA,
                                           float* __restrict__ dOut){
  const int c0 = blockIdx.x * 16;
  const int i = threadIdx.x;
  __shared__ float f2s[256];
  __shared__ float wt[64][36];
  const float f1 = F1B[i];
  f2s[i] = F2B[i];
  unsigned mw[8];
#pragma unroll
  for (int w = 0; w < 8; ++w) mw[w] = maskA[i*8 + w];
  __syncthreads();
  float m = -INFINITY;
  for (int w = 0; w < 8; ++w){
    const unsigned mk = mw[w];
#pragma unroll
    for (int bb = 0; bb < 32; ++bb){
      float e = f1 + f2s[(w<<5)+bb]; e = (e > 0.f) ? e : ALPHA*e;
      e = ((mk >> bb) & 1u) ? e : NEGV;
      m = fmaxf(m, e);
    }
  }
  float s = 0.f;
  for (int w = 0; w < 8; ++w){
    const unsigned mk = mw[w];
#pragma unroll
    for (int bb = 0; bb < 32; ++bb){
      float e = f1 + f2s[(w<<5)+bb]; e = (e > 0.f) ? e : ALPHA*e;
      e = ((mk >> bb) & 1u) ? e : NEGV;
      s += __expf(e - m);
    }
  }
  const float inv = 1.f / s;
  float acc[16];
#pragma unroll
  for (int c = 0; c < 16; ++c) acc[c] = 0.f;
  for (int jt = 0; jt < 4; ++jt){
    __syncthreads();
    for (int idx = i; idx < 1024; idx += 256){
      int cc = idx >> 6, jj = idx & 63;
      wt[jj][cc] = Wh2[(c0+cc)*256 + (jt<<6) + jj];
    }
    __syncthreads();
    for (int jj = 0; jj < 64; ++jj){
      const int j = (jt<<6) + jj;
      float e = f1 + f2s[j]; e = (e > 0.f) ? e : ALPHA*e;
      e = ((mw[j>>5] >> (j & 31)) & 1u) ? e : NEGV;
      const float p = __expf(e - m) * inv;
      const float* wr = &wt[jj][0];
#pragma unroll
      for (int c = 0; c < 16; ++c) acc[c] = fmaf(p, wr[c], acc[c]);
    }
  }
#pragma unroll
  for (int c = 0; c < 16; ++c) dOut[i*64 + c0 + c] = acc[c];
}

extern "C" void kernel_launch(void* const* d_in, const int* in_sizes, int n_in,
                              void* d_out, int out_size, void* d_ws, size_t ws_size,
                              hipStream_t stream){
  (void)in_sizes; (void)n_in; (void)out_size; (void)ws_size;
  const float* x     = (const float*)d_in[0];
  const float* Fadj  = (const float*)d_in[1];
  const float* Tadj  = (const float*)d_in[2];
  const float* adj   = (const float*)d_in[3];
  const float* Hpre  = (const float*)d_in[4];
  const float* FattW = (const float*)d_in[5];
  const float* Fatta = (const float*)d_in[6];
  const float* TattW = (const float*)d_in[7];
  const float* Tatta = (const float*)d_in[8];
  const float* Wih0  = (const float*)d_in[9];
  const float* Whh0  = (const float*)d_in[10];
  const float* bih0  = (const float*)d_in[11];
  const float* bhh0  = (const float*)d_in[12];
  const float* Wih1  = (const float*)d_in[13];
  const float* Whh1  = (const float*)d_in[14];
  const float* bih1  = (const float*)d_in[15];
  const float* bhh1  = (const float*)d_in[16];
  const float* fc1w  = (const float*)d_in[17];
  const float* fc1b  = (const float*)d_in[18];
  const float* fc2w  = (const float*)d_in[19];
  const float* fc2b  = (const float*)d_in[20];
  const float* fc3w  = (const float*)d_in[21];
  const float* fc3b  = (const float*)d_in[22];
  const float* oW    = (const float*)d_in[23];
  const float* oa    = (const float*)d_in[24];
  const float* o1W   = (const float*)d_in[25];
  const float* o1a   = (const float*)d_in[26];
  const float* o2W   = (const float*)d_in[27];
  const float* o2a   = (const float*)d_in[28];
  float* out = (float*)d_out;

  float* ws = (float*)d_ws;
  float* R0 = ws;
  float* R1 = ws + 4194304;
  float* R2 = ws + 8388608;
  unsigned* maskT = (unsigned*)R2;             // 524288 words
  float* Tf1p = R2 + 524288;                   // 2 x 65536
  float* Tf2p = R2 + 655360;                   // 2 x 65536
  unsigned* maskA = (unsigned*)(ws + 12582912);// 2048 words
  float* WhTt = R0;
  float* WhF  = R0;
  float* Gi0  = R0;
  float* TatT = R1;
  float* Fat  = R2;
  float* ctb   = R1;                           // tail (TatT dead after k5)
  float* WhABt = R1 + 16384;
  float* OF1   = R1 + 49152;
  float* OF2   = R1 + 49664;
  float* OUTT  = R1 + 50176;
  float* WH2   = R1 + 82944;
  float* F1B   = R1 + 99328;
  float* F2B   = R1 + 99584;

  k_mask<<<1024, 256, 0, stream>>>(Tadj, maskT, 16777216);
  k_mask<<<32, 256, 0, stream>>>(adj, maskA, 65536);
  k3_wht<<<512, 256, 0, stream>>>(x, TattW, Tatta, WhTt, Tf1p, Tf2p);
  k4_tat<<<512, 256, 0, stream>>>(WhTt, Tf1p, Tf2p, maskT, TatT);
  k1_whf<<<256, 512, 0, stream>>>(x, FattW, WhF);
  k2_fat<<<256, 512, 0, stream>>>(WhF, Fatta, Fadj, Fat);
  k5_gi0<<<256, 512, 0, stream>>>(Fat, TatT, x, Wih0, Gi0);
  k6_gru<<<256, 64, 0, stream>>>(Gi0, Hpre, Whh0, bih0, bhh0, Wih1, Whh1, bih1, bhh1,
                                 fc1w, fc1b, fc2w, fc2b, fc3w, fc3b, ctb, out);
  k8a<<<8, 256, 0, stream>>>(ctb, oW, oa, o1W, o1a, WhABt, OF1, OF2);
  k8b<<<8, 256, 0, stream>>>(WhABt, OF1, OF2, maskA, OUTT);
  k8c<<<8, 256, 0, stream>>>(OUTT, o2W, o2a, WH2, F1B, F2B);
  k8d<<<4, 256, 0, stream>>>(WH2, F1B, F2B, maskA, out);
}